// Round 3
// baseline (765.136 us; speedup 1.0000x reference)
//
#include <hip/hip_runtime.h>
#include <cstdint>
#include <cstddef>

// B=2 L=2048 HIDDEN=2560 NH=16 NKV=4 HD=256 INNER=4096
// QKV combined N = 8192 (q+gate) + 1024 (k) + 1024 (v) = 10240
#define NQKV 10240

typedef __bf16 bf16;
typedef __attribute__((ext_vector_type(4))) __bf16 bvec4;
typedef __attribute__((ext_vector_type(8))) __bf16 bvec8;
typedef __attribute__((ext_vector_type(4))) float fvec4;

__device__ __forceinline__ void gll16(const bf16* g, bf16* l) {
  // async global->LDS, 16B/lane; LDS dest = wave-uniform base + lane*16
  __builtin_amdgcn_global_load_lds(
      (const __attribute__((address_space(1))) void*)g,
      (__attribute__((address_space(3))) void*)l, 16, 0, 0);
}

// ---------------- fp32 -> bf16 flat convert ----------------
__global__ __launch_bounds__(256) void cvt_f32_bf16(const float* __restrict__ x,
                                                    bf16* __restrict__ y, int n) {
  int i = (blockIdx.x * 256 + threadIdx.x) * 4;
  if (i < n) {
    float4 v = *(const float4*)(x + i);
    bvec4 o;
    o.x = (bf16)v.x; o.y = (bf16)v.y; o.z = (bf16)v.z; o.w = (bf16)v.w;
    *(bvec4*)(y + i) = o;
  }
}

// ---------------- W (K x N) fp32 -> Wt (N x K) bf16 ----------------
__global__ __launch_bounds__(256) void wtrans(const float* __restrict__ W,
                                              bf16* __restrict__ Wt, int K, int N) {
  __shared__ float t[64][65];
  int n0 = blockIdx.x * 64, k0 = blockIdx.y * 64;
  int tx = threadIdx.x & 63, tg = threadIdx.x >> 6;
#pragma unroll
  for (int i = 0; i < 16; ++i) {
    int r = tg * 16 + i;
    t[r][tx] = W[(size_t)(k0 + r) * N + n0 + tx];
  }
  __syncthreads();
#pragma unroll
  for (int i = 0; i < 16; ++i) {
    int r = tg * 16 + i;
    Wt[(size_t)(n0 + r) * K + k0 + tx] = (bf16)t[tx][r];
  }
}

// ---------------- V columns of QKV -> Vt (b,kv,d,L) bf16 ----------------
__global__ __launch_bounds__(256) void vtrans(const bf16* __restrict__ QKV,
                                              bf16* __restrict__ Vt) {
  __shared__ bf16 t[64][65];
  int l0 = blockIdx.x * 64, dd0 = blockIdx.y * 64;
  int bkv = blockIdx.z, b = bkv >> 2, kv = bkv & 3;
  int tx = threadIdx.x & 63, tg = threadIdx.x >> 6;
#pragma unroll
  for (int i = 0; i < 16; ++i) {
    int r = tg * 16 + i;
    t[r][tx] = QKV[(size_t)(b * 2048 + l0 + r) * NQKV + 9216 + kv * 256 + dd0 + tx];
  }
  __syncthreads();
#pragma unroll
  for (int i = 0; i < 16; ++i) {
    int r = tg * 16 + i;
    Vt[((size_t)bkv * 256 + dd0 + r) * 2048 + l0 + tx] = t[tx][r];
  }
}

// ---------------- RMSNorm + RoPE: QKV -> Qn (b,h,l,d), Kn (b,kv,l,d) ----------------
__global__ __launch_bounds__(256) void norm_rope(const bf16* __restrict__ QKV,
    const float* __restrict__ cosT, const float* __restrict__ sinT,
    const float* __restrict__ qw, const float* __restrict__ kw,
    bf16* __restrict__ Qn, bf16* __restrict__ Kn) {
  int u = blockIdx.x * 4 + (threadIdx.x >> 6);
  int lane = threadIdx.x & 63;
  int token = u / 20, slot = u - token * 20;
  int b = token >> 11, l = token & 2047;
  int d0 = lane * 4;
  const float* w;
  int col0;
  bf16* outp;
  if (slot < 16) {
    col0 = slot * 256; w = qw;
    outp = Qn + ((size_t)((b * 16 + slot) * 2048 + l)) * 256;
  } else {
    int kv = slot - 16;
    col0 = 8192 + kv * 256; w = kw;
    outp = Kn + ((size_t)((b * 4 + kv) * 2048 + l)) * 256;
  }
  bvec4 xi = *(const bvec4*)(QKV + (size_t)token * NQKV + col0 + d0);
  float x[4];
#pragma unroll
  for (int j = 0; j < 4; ++j) x[j] = (float)xi[j];
  float ss = x[0] * x[0] + x[1] * x[1] + x[2] * x[2] + x[3] * x[3];
#pragma unroll
  for (int off = 32; off; off >>= 1) ss += __shfl_xor(ss, off);
  float rn = rsqrtf(ss * (1.0f / 256.0f) + 1e-6f);
  float xn[4];
#pragma unroll
  for (int j = 0; j < 4; ++j) xn[j] = x[j] * rn * w[d0 + j];
  bvec4 o;
#pragma unroll
  for (int j = 0; j < 4; ++j) {
    float other = __shfl_xor(xn[j], 32);
    float rot = (lane < 32) ? -other : other;
    float c = cosT[(size_t)l * 256 + d0 + j];
    float s = sinT[(size_t)l * 256 + d0 + j];
    o[j] = (bf16)(xn[j] * c + rot * s);
  }
  *(bvec4*)(outp + d0) = o;
}

// ---------------- pipelined GEMM: C[M][N] = A[M][K] * B[N][K]^T ----------------
// Tile 128(M) x 256(N), BK=32. 256 threads = 4 waves (2M x 2N), per-wave
// output 64x128 -> acc[4][8], 32 MFMA + 12 ds_read_b128 per K-step.
// LDS: 3 buffers x 24 KB = 72 KB -> 2 blocks/CU.
// ONE barrier per K-step: vmcnt(6) retires tile t's 6 stages (2 tiles stay
// in flight), s_barrier makes tile t visible AND proves all waves consumed
// tile t-1 (every ds_read feeds an MFMA in its own iteration) -> staging
// tile t+2 into b2 right after the barrier is race-free.
// Swizzle (T2): 16B chunk c of row r at phys chunk c ^ ((r>>1)&3), applied
// on the gll16 *global source* (LDS dest linear) and on the ds_read side.
// XCD swizzle (T1): bijective chunked remap (grid % 8 == 0).
template <typename OutT>
__global__ __launch_bounds__(256, 2) void gemm8(const bf16* __restrict__ A,
                                                const bf16* __restrict__ B,
                                                OutT* __restrict__ C,
                                                int N, int Kd) {
  __shared__ alignas(16) bf16 smem[36864];
  int tid = threadIdx.x, wave = tid >> 6, lane = tid & 63;
  int quad = lane >> 4, l15 = lane & 15;
  int wm = wave >> 1, wn = wave & 1;
  // XCD-aware bijective remap: bn-fastest chunks -> each XCD owns few A rows
  int nbx = gridDim.x;
  int lin = blockIdx.x + nbx * blockIdx.y;
  int cpx = (nbx * gridDim.y) >> 3;
  int swz = (lin & 7) * cpx + (lin >> 3);
  int bn = swz % nbx, bm = swz / nbx;
  const bf16* Ag = A + (size_t)bm * 128 * Kd;
  const bf16* Bg = B + (size_t)bn * 256 * Kd;

  bf16* b0 = smem;
  bf16* b1 = smem + 12288;
  bf16* b2 = smem + 24576;

  int nt = Kd >> 5;
  // staging lane map: row-in-seg = lane>>2, logical chunk = (lane&3)^((lane>>3)&3)
  int srow = lane >> 2;
  int sc8 = ((lane & 3) ^ ((lane >> 3) & 3)) * 8;
  // fragment-read swizzled chunk (row = multiple-of-16 + l15)
  int csw = (quad ^ ((l15 >> 1) & 3)) * 8;

  const fvec4 FZ = {0.f, 0.f, 0.f, 0.f};
  fvec4 acc[4][8];
#pragma unroll
  for (int i = 0; i < 4; ++i)
#pragma unroll
    for (int j = 0; j < 8; ++j) acc[i][j] = FZ;

  // stage one K-tile (24 segs of 1KB: segs 0-7 = A rows, 8-23 = B rows)
  auto stage = [&](bf16* dst, int ktel) {
#pragma unroll
    for (int i = 0; i < 6; ++i) {
      int s = wave * 6 + i;
      if (s < 8) {
        gll16(Ag + (size_t)(s * 16 + srow) * Kd + ktel + sc8, dst + s * 512);
      } else {
        gll16(Bg + (size_t)((s - 8) * 16 + srow) * Kd + ktel + sc8,
              dst + 4096 + (s - 8) * 512);
      }
    }
  };

  // prologue: tiles 0,1 in flight (12 outstanding vmem ops/thread)
  stage(b0, 0);
  stage(b1, 32);

  for (int t = 0; t < nt; ++t) {
    asm volatile("s_waitcnt vmcnt(6)" ::: "memory");  // retire tile t's stages
    __builtin_amdgcn_s_barrier();  // tile t visible; all tile t-1 reads consumed
    int t2 = t + 2;
    if (t2 >= nt) t2 = nt - 1;  // clamp keeps vmcnt ledger uniform
    stage(b2, t2 * 32);         // b2 held tile t-1, fully consumed pre-barrier
    const bf16* Ab = b0;
    const bf16* Bb = b0 + 4096;
    bvec8 af[4], bv[8];
#pragma unroll
    for (int mt = 0; mt < 4; ++mt)
      af[mt] = *(const bvec8*)(Ab + (wm * 64 + mt * 16 + l15) * 32 + csw);
#pragma unroll
    for (int nt2 = 0; nt2 < 8; ++nt2)
      bv[nt2] = *(const bvec8*)(Bb + (wn * 128 + nt2 * 16 + l15) * 32 + csw);
    __builtin_amdgcn_s_setprio(1);
#pragma unroll
    for (int mt = 0; mt < 4; ++mt)
#pragma unroll
      for (int nt2 = 0; nt2 < 8; ++nt2)
        acc[mt][nt2] = __builtin_amdgcn_mfma_f32_16x16x32_bf16(af[mt], bv[nt2],
                                                               acc[mt][nt2], 0, 0, 0);
    __builtin_amdgcn_s_setprio(0);
    bf16* tp = b0; b0 = b1; b1 = b2; b2 = tp;
  }

#pragma unroll
  for (int mt = 0; mt < 4; ++mt)
#pragma unroll
    for (int nt2 = 0; nt2 < 8; ++nt2)
#pragma unroll
      for (int r = 0; r < 4; ++r) {
        int row = bm * 128 + wm * 64 + mt * 16 + quad * 4 + r;
        int col = bn * 256 + wn * 128 + nt2 * 16 + l15;
        C[(size_t)row * N + col] = (OutT)acc[mt][nt2][r];
      }
}

// ---------------- causal flash attention v2 + SiLU-gate epilogue ----------------
// Block = 256 threads (4 waves), each wave owns 16 Q rows. Q-tile = 64 rows.
// K-tile = 64. Causal balance: block pairs Q-tiles (i, 31-i) -> every block
// runs exactly 33 k-tiles; grid 16x32 = 512 blocks, 2/CU.
// P lives in its OWN region (written+read by same wave only) -> no aliasing
// with Ks -> only 2 barriers per k-tile (restage-guard, tiles-visible).
// Defer-max (T13): skip acc rescale unless tile max exceeds m_run + 8.
// XCD swizzle: chunk of 64 blocks = one (b,kvh) group -> K/V XCD-local.
// Ks logical (row,chunk16B c): phys chunk = row*32 + (c ^ (row&31))
// Vts logical (d-row, chunk c): phys chunk = row*8  + (c ^ (row&7))
__global__ __launch_bounds__(256, 2) void flash(const bf16* __restrict__ Q,
    const bf16* __restrict__ K, const bf16* __restrict__ Vt,
    const bf16* __restrict__ QKV, bf16* __restrict__ Og) {
  __shared__ alignas(16) bf16 smem[37376];  // 32K Ks/Vts + 4.5K P
  bf16* Ks = smem;
  bf16* Vts = smem + 16384;

  int lin = blockIdx.x + 16 * blockIdx.y;  // 512 blocks
  int swz = (lin & 7) * 64 + (lin >> 3);
  int pairi = swz & 15;               // 0..15
  int bh = swz >> 4, b = bh >> 4, h = bh & 15, kvh = h >> 2;
  int tid = threadIdx.x, wave = tid >> 6, lane = tid & 63;
  int quad = lane >> 4, l15 = lane & 15;
  bf16* Pw = smem + 32768 + wave * 1152;  // 16 x 72 bf16, private per wave

  const bf16* Qh = Q + ((size_t)(b * 16 + h) * 2048) * 256;
  const bf16* Kb = K + ((size_t)(b * 4 + kvh) * 2048) * 256;
  const bf16* Vb = Vt + ((size_t)(b * 4 + kvh) * 256) * 2048;
  const fvec4 FZ = {0.f, 0.f, 0.f, 0.f};

  for (int half = 0; half < 2; ++half) {
    int qt = half ? (31 - pairi) : pairi;
    int q0 = qt * 64;

    // Q fragments resident, pre-scaled by 1/sqrt(256)=2^-4 (exact in bf16)
    bvec8 qf[8];
    {
      int row = q0 + wave * 16 + l15;
#pragma unroll
      for (int kk = 0; kk < 8; ++kk) {
        bvec8 v = *(const bvec8*)(Qh + (size_t)row * 256 + kk * 32 + quad * 8);
#pragma unroll
        for (int j = 0; j < 8; ++j) v[j] = (bf16)((float)v[j] * 0.0625f);
        qf[kk] = v;
      }
    }

    fvec4 acc[16];
#pragma unroll
    for (int i = 0; i < 16; ++i) acc[i] = FZ;
    float m_run[4], l_run[4];
#pragma unroll
    for (int r = 0; r < 4; ++r) { m_run[r] = -3.0e38f; l_run[r] = 0.f; }

    for (int kt = 0; kt <= qt; ++kt) {
      int k0 = kt * 64;
      __syncthreads();  // prior iter's Ks/Vts readers done before restaging
#pragma unroll
      for (int i = 0; i < 8; ++i) {
        int seg = wave * 8 + i;  // 0..31, 1KB per gll16
        int krow = seg * 2 + (lane >> 5);
        int kc = (lane & 31) ^ (krow & 31);
        gll16(Kb + (size_t)(k0 + krow) * 256 + kc * 8, Ks + seg * 512);
        int vrow = seg * 8 + (lane >> 3);
        int vc = (lane & 7) ^ (vrow & 7);
        gll16(Vb + (size_t)vrow * 2048 + k0 + vc * 8, Vts + seg * 512);
      }
      __syncthreads();  // tiles visible (barrier drains vmcnt)

      // S = Q K^T
      fvec4 s[4];
#pragma unroll
      for (int nt = 0; nt < 4; ++nt) {
        s[nt] = FZ;
        int row = nt * 16 + l15;
        int rm = row & 31;
        __builtin_amdgcn_s_setprio(1);
#pragma unroll
        for (int ks = 0; ks < 8; ++ks) {
          int c = ks * 4 + quad;
          bvec8 kf = *(const bvec8*)(Ks + (size_t)row * 256 + (size_t)(c ^ rm) * 8);
          s[nt] = __builtin_amdgcn_mfma_f32_16x16x32_bf16(qf[ks], kf, s[nt], 0, 0, 0);
        }
        __builtin_amdgcn_s_setprio(0);
      }

      if (kt == qt) {  // only the diagonal tile masks
#pragma unroll
        for (int nt = 0; nt < 4; ++nt)
#pragma unroll
          for (int r = 0; r < 4; ++r)
            if (k0 + nt * 16 + l15 > q0 + wave * 16 + quad * 4 + r)
              s[nt][r] = -3.0e38f;
      }

      // online softmax with defer-max (THR=8)
      {
        float pmax[4];
#pragma unroll
        for (int r = 0; r < 4; ++r) {
          float m = fmaxf(fmaxf(s[0][r], s[1][r]),
                          fmaxf(s[2][r], s[3][r]));
#pragma unroll
          for (int off = 8; off; off >>= 1) m = fmaxf(m, __shfl_xor(m, off));
          pmax[r] = m;
        }
        int need = 0;
#pragma unroll
        for (int r = 0; r < 4; ++r) need |= (pmax[r] > m_run[r] + 8.0f) ? 1 : 0;
        if (__any(need)) {
#pragma unroll
          for (int r = 0; r < 4; ++r) {
            float Mn = fmaxf(m_run[r], pmax[r]);
            float alpha = __expf(m_run[r] - Mn);
            m_run[r] = Mn;
            l_run[r] *= alpha;
#pragma unroll
            for (int nt = 0; nt < 16; ++nt) acc[nt][r] *= alpha;
          }
        }
        float rs[4] = {0.f, 0.f, 0.f, 0.f};
#pragma unroll
        for (int nt = 0; nt < 4; ++nt)
#pragma unroll
          for (int r = 0; r < 4; ++r) {
            float p = __expf(s[nt][r] - m_run[r]);
            rs[r] += p;
            Pw[(quad * 4 + r) * 72 + nt * 16 + l15] = (bf16)p;
          }
#pragma unroll
        for (int r = 0; r < 4; ++r) {
#pragma unroll
          for (int off = 8; off; off >>= 1) rs[r] += __shfl_xor(rs[r], off);
          l_run[r] += rs[r];
        }
      }

      // O += P (16x64) * Vtile (64x256); same-wave P RAW -> compiler lgkmcnt
#pragma unroll
      for (int ks = 0; ks < 2; ++ks) {
        bvec8 pf = *(const bvec8*)(Pw + l15 * 72 + ks * 32 + quad * 8);
        __builtin_amdgcn_s_setprio(1);
#pragma unroll
        for (int nt = 0; nt < 16; ++nt) {
          int row = nt * 16 + l15;
          int c = ks * 4 + quad;
          bvec8 vf = *(const bvec8*)(Vts + (size_t)row * 64 + (size_t)(c ^ (row & 7)) * 8);
          acc[nt] = __builtin_amdgcn_mfma_f32_16x16x32_bf16(pf, vf, acc[nt], 0, 0, 0);
        }
        __builtin_amdgcn_s_setprio(0);
      }
    }

    // epilogue: O/l * silu(gate), token-major (b*2048+l, h*256+d)
#pragma unroll
    for (int r = 0; r < 4; ++r) {
      int token = b * 2048 + q0 + wave * 16 + quad * 4 + r;
      float inv = 1.0f / l_run[r];
#pragma unroll
      for (int nt = 0; nt < 16; ++nt) {
        int col = h * 256 + nt * 16 + l15;
        float g = (float)QKV[(size_t)token * NQKV + 4096 + col];
        float silu = g / (1.0f + __expf(-g));
        Og[(size_t)token * 4096 + col] = (bf16)(acc[nt][r] * inv * silu);
      }
    }
  }
}

extern "C" void kernel_launch(void* const* d_in, const int* in_sizes, int n_in,
                              void* d_out, int out_size, void* d_ws, size_t ws_size,
                              hipStream_t stream) {
  const float* hs   = (const float*)d_in[0];
  const float* cosT = (const float*)d_in[1];
  const float* sinT = (const float*)d_in[2];
  const float* Wq   = (const float*)d_in[3];
  const float* Wk   = (const float*)d_in[4];
  const float* Wv   = (const float*)d_in[5];
  const float* Wo   = (const float*)d_in[6];
  const float* qw   = (const float*)d_in[7];
  const float* kw   = (const float*)d_in[8];
  float* out = (float*)d_out;

  char* p = (char*)d_ws;
  auto alloc = [&](size_t bytes) {
    char* r = p;
    p += (bytes + 255) & ~(size_t)255;
    return r;
  };
  bf16* Xb    = (bf16*)alloc((size_t)4096 * 2560 * 2);
  bf16* Wqkvt = (bf16*)alloc((size_t)10240 * 2560 * 2);
  bf16* Wot   = (bf16*)alloc((size_t)2560 * 4096 * 2);
  bf16* QKV   = (bf16*)alloc((size_t)4096 * 10240 * 2);
  bf16* Qn    = (bf16*)alloc((size_t)2 * 16 * 2048 * 256 * 2);
  bf16* Kn    = (bf16*)alloc((size_t)2 * 4 * 2048 * 256 * 2);
  bf16* Vtb   = (bf16*)alloc((size_t)2 * 4 * 256 * 2048 * 2);
  bf16* Og    = (bf16*)alloc((size_t)4096 * 4096 * 2);

  cvt_f32_bf16<<<10240, 256, 0, stream>>>(hs, Xb, 4096 * 2560);
  wtrans<<<dim3(128, 40), 256, 0, stream>>>(Wq, Wqkvt, 2560, 8192);
  wtrans<<<dim3(16, 40), 256, 0, stream>>>(Wk, Wqkvt + (size_t)8192 * 2560, 2560, 1024);
  wtrans<<<dim3(16, 40), 256, 0, stream>>>(Wv, Wqkvt + (size_t)9216 * 2560, 2560, 1024);
  wtrans<<<dim3(40, 64), 256, 0, stream>>>(Wo, Wot, 4096, 2560);

  gemm8<bf16><<<dim3(40, 32), 256, 0, stream>>>(Xb, Wqkvt, QKV, 10240, 2560);

  norm_rope<<<20480, 256, 0, stream>>>(QKV, cosT, sinT, qw, kw, Qn, Kn);
  vtrans<<<dim3(32, 4, 8), 256, 0, stream>>>(QKV, Vtb);

  flash<<<dim3(16, 32), 256, 0, stream>>>(Qn, Kn, Vtb, QKV, Og);

  gemm8<float><<<dim3(10, 32), 256, 0, stream>>>(Og, Wot, out, 2560, 4096);
}

// Round 4
// 752.626 us; speedup vs baseline: 1.0166x; 1.0166x over previous
//
#include <hip/hip_runtime.h>
#include <cstdint>
#include <cstddef>

// B=2 L=2048 HIDDEN=2560 NH=16 NKV=4 HD=256 INNER=4096
// QKV combined N = 8192 (q+gate) + 1024 (k) + 1024 (v) = 10240
#define NQKV 10240

typedef __bf16 bf16;
typedef __attribute__((ext_vector_type(4))) __bf16 bvec4;
typedef __attribute__((ext_vector_type(8))) __bf16 bvec8;
typedef __attribute__((ext_vector_type(4))) float fvec4;

__device__ __forceinline__ void gll16(const bf16* g, bf16* l) {
  // async global->LDS, 16B/lane; LDS dest = wave-uniform base + lane*16
  __builtin_amdgcn_global_load_lds(
      (const __attribute__((address_space(1))) void*)g,
      (__attribute__((address_space(3))) void*)l, 16, 0, 0);
}

// ---------------- fp32 -> bf16 flat convert ----------------
__global__ __launch_bounds__(256) void cvt_f32_bf16(const float* __restrict__ x,
                                                    bf16* __restrict__ y, int n) {
  int i = (blockIdx.x * 256 + threadIdx.x) * 4;
  if (i < n) {
    float4 v = *(const float4*)(x + i);
    bvec4 o;
    o.x = (bf16)v.x; o.y = (bf16)v.y; o.z = (bf16)v.z; o.w = (bf16)v.w;
    *(bvec4*)(y + i) = o;
  }
}

// ---------------- W (K x N) fp32 -> Wt (N x K) bf16 ----------------
__global__ __launch_bounds__(256) void wtrans(const float* __restrict__ W,
                                              bf16* __restrict__ Wt, int K, int N) {
  __shared__ float t[64][65];
  int n0 = blockIdx.x * 64, k0 = blockIdx.y * 64;
  int tx = threadIdx.x & 63, tg = threadIdx.x >> 6;
#pragma unroll
  for (int i = 0; i < 16; ++i) {
    int r = tg * 16 + i;
    t[r][tx] = W[(size_t)(k0 + r) * N + n0 + tx];
  }
  __syncthreads();
#pragma unroll
  for (int i = 0; i < 16; ++i) {
    int r = tg * 16 + i;
    Wt[(size_t)(n0 + r) * K + k0 + tx] = (bf16)t[tx][r];
  }
}

// ---------------- V columns of QKV -> Vt (b,kv,d,L) bf16 ----------------
__global__ __launch_bounds__(256) void vtrans(const bf16* __restrict__ QKV,
                                              bf16* __restrict__ Vt) {
  __shared__ bf16 t[64][65];
  int l0 = blockIdx.x * 64, dd0 = blockIdx.y * 64;
  int bkv = blockIdx.z, b = bkv >> 2, kv = bkv & 3;
  int tx = threadIdx.x & 63, tg = threadIdx.x >> 6;
#pragma unroll
  for (int i = 0; i < 16; ++i) {
    int r = tg * 16 + i;
    t[r][tx] = QKV[(size_t)(b * 2048 + l0 + r) * NQKV + 9216 + kv * 256 + dd0 + tx];
  }
  __syncthreads();
#pragma unroll
  for (int i = 0; i < 16; ++i) {
    int r = tg * 16 + i;
    Vt[((size_t)bkv * 256 + dd0 + r) * 2048 + l0 + tx] = t[tx][r];
  }
}

// ---------------- RMSNorm + RoPE: QKV -> Qn (b,h,l,d), Kn (b,kv,l,d) ----------------
__global__ __launch_bounds__(256) void norm_rope(const bf16* __restrict__ QKV,
    const float* __restrict__ cosT, const float* __restrict__ sinT,
    const float* __restrict__ qw, const float* __restrict__ kw,
    bf16* __restrict__ Qn, bf16* __restrict__ Kn) {
  int u = blockIdx.x * 4 + (threadIdx.x >> 6);
  int lane = threadIdx.x & 63;
  int token = u / 20, slot = u - token * 20;
  int b = token >> 11, l = token & 2047;
  int d0 = lane * 4;
  const float* w;
  int col0;
  bf16* outp;
  if (slot < 16) {
    col0 = slot * 256; w = qw;
    outp = Qn + ((size_t)((b * 16 + slot) * 2048 + l)) * 256;
  } else {
    int kv = slot - 16;
    col0 = 8192 + kv * 256; w = kw;
    outp = Kn + ((size_t)((b * 4 + kv) * 2048 + l)) * 256;
  }
  bvec4 xi = *(const bvec4*)(QKV + (size_t)token * NQKV + col0 + d0);
  float x[4];
#pragma unroll
  for (int j = 0; j < 4; ++j) x[j] = (float)xi[j];
  float ss = x[0] * x[0] + x[1] * x[1] + x[2] * x[2] + x[3] * x[3];
#pragma unroll
  for (int off = 32; off; off >>= 1) ss += __shfl_xor(ss, off);
  float rn = rsqrtf(ss * (1.0f / 256.0f) + 1e-6f);
  float xn[4];
#pragma unroll
  for (int j = 0; j < 4; ++j) xn[j] = x[j] * rn * w[d0 + j];
  bvec4 o;
#pragma unroll
  for (int j = 0; j < 4; ++j) {
    float other = __shfl_xor(xn[j], 32);
    float rot = (lane < 32) ? -other : other;
    float c = cosT[(size_t)l * 256 + d0 + j];
    float s = sinT[(size_t)l * 256 + d0 + j];
    o[j] = (bf16)(xn[j] * c + rot * s);
  }
  *(bvec4*)(outp + d0) = o;
}

// ---------------- pipelined GEMM: C[M][N] = A[M][K] * B[N][K]^T ----------------
// Tile 128(M) x 256(N), BK=32. 256 threads = 4 waves (2M x 2N), per-wave
// output 64x128 -> acc[4][8], 32 MFMA + 12 ds_read_b128 per K-step.
// LDS: 3 buffers x 24 KB = 72 KB -> 2 blocks/CU.
// ONE barrier per K-step: vmcnt(6) retires tile t's 6 stages (2 tiles stay
// in flight), s_barrier makes tile t visible AND proves all waves consumed
// tile t-1 (every ds_read is consumed by an MFMA in its own iteration, and
// MFMA issue forces the lgkmcnt wait) -> staging tile t+2 into b2 right
// after the barrier is race-free.
// Swizzle (T2): 16B chunk c of row r at phys chunk c ^ ((r>>1)&3), applied
// on the gll16 *global source* (LDS dest linear) and on the ds_read side.
// NO XCD remap: inputs (A 20MB + B 52MB) are L3-resident; natural
// bn-fastest dispatch keeps the A-panel hot per-XCD and B walked
// coherently (r3's chunked remap blew FETCH 218MB -> 843MB, +27us).
template <typename OutT>
__global__ __launch_bounds__(256, 2) void gemm8(const bf16* __restrict__ A,
                                                const bf16* __restrict__ B,
                                                OutT* __restrict__ C,
                                                int N, int Kd) {
  __shared__ alignas(16) bf16 smem[36864];
  int tid = threadIdx.x, wave = tid >> 6, lane = tid & 63;
  int quad = lane >> 4, l15 = lane & 15;
  int wm = wave >> 1, wn = wave & 1;
  int bm = blockIdx.y, bn = blockIdx.x;
  const bf16* Ag = A + (size_t)bm * 128 * Kd;
  const bf16* Bg = B + (size_t)bn * 256 * Kd;

  bf16* b0 = smem;
  bf16* b1 = smem + 12288;
  bf16* b2 = smem + 24576;

  int nt = Kd >> 5;
  // staging lane map: row-in-seg = lane>>2, logical chunk = (lane&3)^((lane>>3)&3)
  int srow = lane >> 2;
  int sc8 = ((lane & 3) ^ ((lane >> 3) & 3)) * 8;
  // fragment-read swizzled chunk (row = multiple-of-16 + l15)
  int csw = (quad ^ ((l15 >> 1) & 3)) * 8;

  const fvec4 FZ = {0.f, 0.f, 0.f, 0.f};
  fvec4 acc[4][8];
#pragma unroll
  for (int i = 0; i < 4; ++i)
#pragma unroll
    for (int j = 0; j < 8; ++j) acc[i][j] = FZ;

  // stage one K-tile (24 segs of 1KB: segs 0-7 = A rows, 8-23 = B rows)
  auto stage = [&](bf16* dst, int ktel) {
#pragma unroll
    for (int i = 0; i < 6; ++i) {
      int s = wave * 6 + i;
      if (s < 8) {
        gll16(Ag + (size_t)(s * 16 + srow) * Kd + ktel + sc8, dst + s * 512);
      } else {
        gll16(Bg + (size_t)((s - 8) * 16 + srow) * Kd + ktel + sc8,
              dst + 4096 + (s - 8) * 512);
      }
    }
  };

  // prologue: tiles 0,1 in flight (12 outstanding vmem ops/thread)
  stage(b0, 0);
  stage(b1, 32);

  for (int t = 0; t < nt; ++t) {
    asm volatile("s_waitcnt vmcnt(6)" ::: "memory");  // retire tile t's stages
    __builtin_amdgcn_s_barrier();  // tile t visible; all tile t-1 reads consumed
    int t2 = t + 2;
    if (t2 >= nt) t2 = nt - 1;  // clamp keeps vmcnt ledger uniform
    stage(b2, t2 * 32);         // b2 held tile t-1, fully consumed pre-barrier
    const bf16* Ab = b0;
    const bf16* Bb = b0 + 4096;
    bvec8 af[4], bv[8];
#pragma unroll
    for (int mt = 0; mt < 4; ++mt)
      af[mt] = *(const bvec8*)(Ab + (wm * 64 + mt * 16 + l15) * 32 + csw);
#pragma unroll
    for (int nt2 = 0; nt2 < 8; ++nt2)
      bv[nt2] = *(const bvec8*)(Bb + (wn * 128 + nt2 * 16 + l15) * 32 + csw);
    __builtin_amdgcn_s_setprio(1);
#pragma unroll
    for (int mt = 0; mt < 4; ++mt)
#pragma unroll
      for (int nt2 = 0; nt2 < 8; ++nt2)
        acc[mt][nt2] = __builtin_amdgcn_mfma_f32_16x16x32_bf16(af[mt], bv[nt2],
                                                               acc[mt][nt2], 0, 0, 0);
    __builtin_amdgcn_s_setprio(0);
    bf16* tp = b0; b0 = b1; b1 = b2; b2 = tp;
  }

#pragma unroll
  for (int mt = 0; mt < 4; ++mt)
#pragma unroll
    for (int nt2 = 0; nt2 < 8; ++nt2)
#pragma unroll
      for (int r = 0; r < 4; ++r) {
        int row = bm * 128 + wm * 64 + mt * 16 + quad * 4 + r;
        int col = bn * 256 + wn * 128 + nt2 * 16 + l15;
        C[(size_t)row * N + col] = (OutT)acc[mt][nt2][r];
      }
}

// ---------------- causal flash attention v2 + SiLU-gate epilogue ----------------
// Block = 256 threads (4 waves), each wave owns 16 Q rows. Q-tile = 64 rows.
// K-tile = 64. Causal balance: block pairs Q-tiles (i, 31-i) -> every block
// runs exactly 33 k-tiles; grid 16x32 = 512 blocks, 2/CU.
// P lives in its OWN region (written+read by same wave only) -> no aliasing
// with Ks -> only 2 barriers per k-tile (restage-guard, tiles-visible).
// Defer-max (T13): skip acc rescale unless tile max exceeds m_run + 8.
// XCD swizzle: chunk of 64 blocks = one (b,kvh) group -> K/V XCD-local.
// Ks logical (row,chunk16B c): phys chunk = row*32 + (c ^ (row&31))
// Vts logical (d-row, chunk c): phys chunk = row*8  + (c ^ (row&7))
__global__ __launch_bounds__(256, 2) void flash(const bf16* __restrict__ Q,
    const bf16* __restrict__ K, const bf16* __restrict__ Vt,
    const bf16* __restrict__ QKV, bf16* __restrict__ Og) {
  __shared__ alignas(16) bf16 smem[37376];  // 32K Ks/Vts + 4.5K P
  bf16* Ks = smem;
  bf16* Vts = smem + 16384;

  int lin = blockIdx.x + 16 * blockIdx.y;  // 512 blocks
  int swz = (lin & 7) * 64 + (lin >> 3);
  int pairi = swz & 15;               // 0..15
  int bh = swz >> 4, b = bh >> 4, h = bh & 15, kvh = h >> 2;
  int tid = threadIdx.x, wave = tid >> 6, lane = tid & 63;
  int quad = lane >> 4, l15 = lane & 15;
  bf16* Pw = smem + 32768 + wave * 1152;  // 16 x 72 bf16, private per wave

  const bf16* Qh = Q + ((size_t)(b * 16 + h) * 2048) * 256;
  const bf16* Kb = K + ((size_t)(b * 4 + kvh) * 2048) * 256;
  const bf16* Vb = Vt + ((size_t)(b * 4 + kvh) * 256) * 2048;
  const fvec4 FZ = {0.f, 0.f, 0.f, 0.f};

  for (int half = 0; half < 2; ++half) {
    int qt = half ? (31 - pairi) : pairi;
    int q0 = qt * 64;

    // Q fragments resident, pre-scaled by 1/sqrt(256)=2^-4 (exact in bf16)
    bvec8 qf[8];
    {
      int row = q0 + wave * 16 + l15;
#pragma unroll
      for (int kk = 0; kk < 8; ++kk) {
        bvec8 v = *(const bvec8*)(Qh + (size_t)row * 256 + kk * 32 + quad * 8);
#pragma unroll
        for (int j = 0; j < 8; ++j) v[j] = (bf16)((float)v[j] * 0.0625f);
        qf[kk] = v;
      }
    }

    fvec4 acc[16];
#pragma unroll
    for (int i = 0; i < 16; ++i) acc[i] = FZ;
    float m_run[4], l_run[4];
#pragma unroll
    for (int r = 0; r < 4; ++r) { m_run[r] = -3.0e38f; l_run[r] = 0.f; }

    for (int kt = 0; kt <= qt; ++kt) {
      int k0 = kt * 64;
      __syncthreads();  // prior iter's Ks/Vts readers done before restaging
#pragma unroll
      for (int i = 0; i < 8; ++i) {
        int seg = wave * 8 + i;  // 0..31, 1KB per gll16
        int krow = seg * 2 + (lane >> 5);
        int kc = (lane & 31) ^ (krow & 31);
        gll16(Kb + (size_t)(k0 + krow) * 256 + kc * 8, Ks + seg * 512);
        int vrow = seg * 8 + (lane >> 3);
        int vc = (lane & 7) ^ (vrow & 7);
        gll16(Vb + (size_t)vrow * 2048 + k0 + vc * 8, Vts + seg * 512);
      }
      __syncthreads();  // tiles visible (barrier drains vmcnt)

      // S = Q K^T
      fvec4 s[4];
#pragma unroll
      for (int nt = 0; nt < 4; ++nt) {
        s[nt] = FZ;
        int row = nt * 16 + l15;
        int rm = row & 31;
        __builtin_amdgcn_s_setprio(1);
#pragma unroll
        for (int ks = 0; ks < 8; ++ks) {
          int c = ks * 4 + quad;
          bvec8 kf = *(const bvec8*)(Ks + (size_t)row * 256 + (size_t)(c ^ rm) * 8);
          s[nt] = __builtin_amdgcn_mfma_f32_16x16x32_bf16(qf[ks], kf, s[nt], 0, 0, 0);
        }
        __builtin_amdgcn_s_setprio(0);
      }

      if (kt == qt) {  // only the diagonal tile masks
#pragma unroll
        for (int nt = 0; nt < 4; ++nt)
#pragma unroll
          for (int r = 0; r < 4; ++r)
            if (k0 + nt * 16 + l15 > q0 + wave * 16 + quad * 4 + r)
              s[nt][r] = -3.0e38f;
      }

      // online softmax with defer-max (THR=8)
      {
        float pmax[4];
#pragma unroll
        for (int r = 0; r < 4; ++r) {
          float m = fmaxf(fmaxf(s[0][r], s[1][r]),
                          fmaxf(s[2][r], s[3][r]));
#pragma unroll
          for (int off = 8; off; off >>= 1) m = fmaxf(m, __shfl_xor(m, off));
          pmax[r] = m;
        }
        int need = 0;
#pragma unroll
        for (int r = 0; r < 4; ++r) need |= (pmax[r] > m_run[r] + 8.0f) ? 1 : 0;
        if (__any(need)) {
#pragma unroll
          for (int r = 0; r < 4; ++r) {
            float Mn = fmaxf(m_run[r], pmax[r]);
            float alpha = __expf(m_run[r] - Mn);
            m_run[r] = Mn;
            l_run[r] *= alpha;
#pragma unroll
            for (int nt = 0; nt < 16; ++nt) acc[nt][r] *= alpha;
          }
        }
        float rs[4] = {0.f, 0.f, 0.f, 0.f};
#pragma unroll
        for (int nt = 0; nt < 4; ++nt)
#pragma unroll
          for (int r = 0; r < 4; ++r) {
            float p = __expf(s[nt][r] - m_run[r]);
            rs[r] += p;
            Pw[(quad * 4 + r) * 72 + nt * 16 + l15] = (bf16)p;
          }
#pragma unroll
        for (int r = 0; r < 4; ++r) {
#pragma unroll
          for (int off = 8; off; off >>= 1) rs[r] += __shfl_xor(rs[r], off);
          l_run[r] += rs[r];
        }
      }

      // O += P (16x64) * Vtile (64x256); same-wave P RAW -> compiler lgkmcnt
#pragma unroll
      for (int ks = 0; ks < 2; ++ks) {
        bvec8 pf = *(const bvec8*)(Pw + l15 * 72 + ks * 32 + quad * 8);
        __builtin_amdgcn_s_setprio(1);
#pragma unroll
        for (int nt = 0; nt < 16; ++nt) {
          int row = nt * 16 + l15;
          int c = ks * 4 + quad;
          bvec8 vf = *(const bvec8*)(Vts + (size_t)row * 64 + (size_t)(c ^ (row & 7)) * 8);
          acc[nt] = __builtin_amdgcn_mfma_f32_16x16x32_bf16(pf, vf, acc[nt], 0, 0, 0);
        }
        __builtin_amdgcn_s_setprio(0);
      }
    }

    // epilogue: O/l * silu(gate), token-major (b*2048+l, h*256+d)
#pragma unroll
    for (int r = 0; r < 4; ++r) {
      int token = b * 2048 + q0 + wave * 16 + quad * 4 + r;
      float inv = 1.0f / l_run[r];
#pragma unroll
      for (int nt = 0; nt < 16; ++nt) {
        int col = h * 256 + nt * 16 + l15;
        float g = (float)QKV[(size_t)token * NQKV + 4096 + col];
        float silu = g / (1.0f + __expf(-g));
        Og[(size_t)token * 4096 + col] = (bf16)(acc[nt][r] * inv * silu);
      }
    }
  }
}

extern "C" void kernel_launch(void* const* d_in, const int* in_sizes, int n_in,
                              void* d_out, int out_size, void* d_ws, size_t ws_size,
                              hipStream_t stream) {
  const float* hs   = (const float*)d_in[0];
  const float* cosT = (const float*)d_in[1];
  const float* sinT = (const float*)d_in[2];
  const float* Wq   = (const float*)d_in[3];
  const float* Wk   = (const float*)d_in[4];
  const float* Wv   = (const float*)d_in[5];
  const float* Wo   = (const float*)d_in[6];
  const float* qw   = (const float*)d_in[7];
  const float* kw   = (const float*)d_in[8];
  float* out = (float*)d_out;

  char* p = (char*)d_ws;
  auto alloc = [&](size_t bytes) {
    char* r = p;
    p += (bytes + 255) & ~(size_t)255;
    return r;
  };
  bf16* Xb    = (bf16*)alloc((size_t)4096 * 2560 * 2);
  bf16* Wqkvt = (bf16*)alloc((size_t)10240 * 2560 * 2);
  bf16* Wot   = (bf16*)alloc((size_t)2560 * 4096 * 2);
  bf16* QKV   = (bf16*)alloc((size_t)4096 * 10240 * 2);
  bf16* Qn    = (bf16*)alloc((size_t)2 * 16 * 2048 * 256 * 2);
  bf16* Kn    = (bf16*)alloc((size_t)2 * 4 * 2048 * 256 * 2);
  bf16* Vtb   = (bf16*)alloc((size_t)2 * 4 * 256 * 2048 * 2);
  bf16* Og    = (bf16*)alloc((size_t)4096 * 4096 * 2);

  cvt_f32_bf16<<<10240, 256, 0, stream>>>(hs, Xb, 4096 * 2560);
  wtrans<<<dim3(128, 40), 256, 0, stream>>>(Wq, Wqkvt, 2560, 8192);
  wtrans<<<dim3(16, 40), 256, 0, stream>>>(Wk, Wqkvt + (size_t)8192 * 2560, 2560, 1024);
  wtrans<<<dim3(16, 40), 256, 0, stream>>>(Wv, Wqkvt + (size_t)9216 * 2560, 2560, 1024);
  wtrans<<<dim3(40, 64), 256, 0, stream>>>(Wo, Wot, 4096, 2560);

  gemm8<bf16><<<dim3(40, 32), 256, 0, stream>>>(Xb, Wqkvt, QKV, 10240, 2560);

  norm_rope<<<20480, 256, 0, stream>>>(QKV, cosT, sinT, qw, kw, Qn, Kn);
  vtrans<<<dim3(32, 4, 8), 256, 0, stream>>>(QKV, Vtb);

  flash<<<dim3(16, 32), 256, 0, stream>>>(Qn, Kn, Vtb, QKV, Og);

  gemm8<float><<<dim3(10, 32), 256, 0, stream>>>(Og, Wot, out, 2560, 4096);
}

// Round 6
// 725.588 us; speedup vs baseline: 1.0545x; 1.0373x over previous
//
#include <hip/hip_runtime.h>
#include <cstdint>
#include <cstddef>

// B=2 L=2048 HIDDEN=2560 NH=16 NKV=4 HD=256 INNER=4096
// QKV combined N = 8192 (q+gate) + 1024 (k) + 1024 (v) = 10240
#define NQKV 10240

typedef __bf16 bf16;
typedef __attribute__((ext_vector_type(4))) __bf16 bvec4;
typedef __attribute__((ext_vector_type(8))) __bf16 bvec8;
typedef __attribute__((ext_vector_type(4))) float fvec4;

__device__ __forceinline__ void gll16(const bf16* g, bf16* l) {
  // async global->LDS, 16B/lane; LDS dest = wave-uniform base + lane*16
  __builtin_amdgcn_global_load_lds(
      (const __attribute__((address_space(1))) void*)g,
      (__attribute__((address_space(3))) void*)l, 16, 0, 0);
}

// ---------------- fp32 -> bf16 flat convert ----------------
__global__ __launch_bounds__(256) void cvt_f32_bf16(const float* __restrict__ x,
                                                    bf16* __restrict__ y, int n) {
  int i = (blockIdx.x * 256 + threadIdx.x) * 4;
  if (i < n) {
    float4 v = *(const float4*)(x + i);
    bvec4 o;
    o.x = (bf16)v.x; o.y = (bf16)v.y; o.z = (bf16)v.z; o.w = (bf16)v.w;
    *(bvec4*)(y + i) = o;
  }
}

// ---------------- W (K x N) fp32 -> Wt (N x K) bf16 ----------------
__global__ __launch_bounds__(256) void wtrans(const float* __restrict__ W,
                                              bf16* __restrict__ Wt, int K, int N) {
  __shared__ float t[64][65];
  int n0 = blockIdx.x * 64, k0 = blockIdx.y * 64;
  int tx = threadIdx.x & 63, tg = threadIdx.x >> 6;
#pragma unroll
  for (int i = 0; i < 16; ++i) {
    int r = tg * 16 + i;
    t[r][tx] = W[(size_t)(k0 + r) * N + n0 + tx];
  }
  __syncthreads();
#pragma unroll
  for (int i = 0; i < 16; ++i) {
    int r = tg * 16 + i;
    Wt[(size_t)(n0 + r) * K + k0 + tx] = (bf16)t[tx][r];
  }
}

// ---------------- V columns of QKV -> Vt (b,kv,d,L) bf16 ----------------
__global__ __launch_bounds__(256) void vtrans(const bf16* __restrict__ QKV,
                                              bf16* __restrict__ Vt) {
  __shared__ bf16 t[64][65];
  int l0 = blockIdx.x * 64, dd0 = blockIdx.y * 64;
  int bkv = blockIdx.z, b = bkv >> 2, kv = bkv & 3;
  int tx = threadIdx.x & 63, tg = threadIdx.x >> 6;
#pragma unroll
  for (int i = 0; i < 16; ++i) {
    int r = tg * 16 + i;
    t[r][tx] = QKV[(size_t)(b * 2048 + l0 + r) * NQKV + 9216 + kv * 256 + dd0 + tx];
  }
  __syncthreads();
#pragma unroll
  for (int i = 0; i < 16; ++i) {
    int r = tg * 16 + i;
    Vt[((size_t)bkv * 256 + dd0 + r) * 2048 + l0 + tx] = t[tx][r];
  }
}

// ---------------- RMSNorm + RoPE: QKV -> Qn (b,h,l,d), Kn (b,kv,l,d) ----------------
__global__ __launch_bounds__(256) void norm_rope(const bf16* __restrict__ QKV,
    const float* __restrict__ cosT, const float* __restrict__ sinT,
    const float* __restrict__ qw, const float* __restrict__ kw,
    bf16* __restrict__ Qn, bf16* __restrict__ Kn) {
  int u = blockIdx.x * 4 + (threadIdx.x >> 6);
  int lane = threadIdx.x & 63;
  int token = u / 20, slot = u - token * 20;
  int b = token >> 11, l = token & 2047;
  int d0 = lane * 4;
  const float* w;
  int col0;
  bf16* outp;
  if (slot < 16) {
    col0 = slot * 256; w = qw;
    outp = Qn + ((size_t)((b * 16 + slot) * 2048 + l)) * 256;
  } else {
    int kv = slot - 16;
    col0 = 8192 + kv * 256; w = kw;
    outp = Kn + ((size_t)((b * 4 + kv) * 2048 + l)) * 256;
  }
  bvec4 xi = *(const bvec4*)(QKV + (size_t)token * NQKV + col0 + d0);
  float x[4];
#pragma unroll
  for (int j = 0; j < 4; ++j) x[j] = (float)xi[j];
  float ss = x[0] * x[0] + x[1] * x[1] + x[2] * x[2] + x[3] * x[3];
#pragma unroll
  for (int off = 32; off; off >>= 1) ss += __shfl_xor(ss, off);
  float rn = rsqrtf(ss * (1.0f / 256.0f) + 1e-6f);
  float xn[4];
#pragma unroll
  for (int j = 0; j < 4; ++j) xn[j] = x[j] * rn * w[d0 + j];
  bvec4 o;
#pragma unroll
  for (int j = 0; j < 4; ++j) {
    float other = __shfl_xor(xn[j], 32);
    float rot = (lane < 32) ? -other : other;
    float c = cosT[(size_t)l * 256 + d0 + j];
    float s = sinT[(size_t)l * 256 + d0 + j];
    o[j] = (bf16)(xn[j] * c + rot * s);
  }
  *(bvec4*)(outp + d0) = o;
}

// ---------------- pipelined GEMM: C[M][N] = A[M][K] * B[N][K]^T ----------------
// Tile 128(M) x 256(N), BK=32. 256 threads = 4 waves (2M x 2N), per-wave
// output 64x128 -> acc[4][8], 32 MFMA + 12 ds_read_b128 per K-step.
// LDS: 3 buffers x 24 KB = 72 KB -> 2 blocks/CU.
// ONE barrier per K-step: vmcnt(6) retires tile t's 6 stages (2 tiles stay
// in flight), s_barrier makes tile t visible AND proves all waves consumed
// tile t-1. Stage for t+2 is issued AFTER the fragment ds_reads so the
// reads start immediately post-barrier and gll16 addr-calc overlaps MFMA.
// Swizzle (T2): 16B chunk c of row r at phys chunk c ^ ((r>>1)&3), applied
// on the gll16 *global source* (LDS dest linear) and on the ds_read side.
// NO XCD remap: inputs are L3-resident; natural bn-fastest dispatch is
// L2/L3-friendly (r3's chunked remap blew FETCH 218MB -> 843MB).
template <typename OutT>
__global__ __launch_bounds__(256, 2) void gemm8(const bf16* __restrict__ A,
                                                const bf16* __restrict__ B,
                                                OutT* __restrict__ C,
                                                int N, int Kd) {
  __shared__ alignas(16) bf16 smem[36864];
  int tid = threadIdx.x, wave = tid >> 6, lane = tid & 63;
  int quad = lane >> 4, l15 = lane & 15;
  int wm = wave >> 1, wn = wave & 1;
  int bm = blockIdx.y, bn = blockIdx.x;
  const bf16* Ag = A + (size_t)bm * 128 * Kd;
  const bf16* Bg = B + (size_t)bn * 256 * Kd;

  bf16* b0 = smem;
  bf16* b1 = smem + 12288;
  bf16* b2 = smem + 24576;

  int nt = Kd >> 5;
  // staging lane map: row-in-seg = lane>>2, logical chunk = (lane&3)^((lane>>3)&3)
  int srow = lane >> 2;
  int sc8 = ((lane & 3) ^ ((lane >> 3) & 3)) * 8;
  // fragment-read swizzled chunk (row = multiple-of-16 + l15)
  int csw = (quad ^ ((l15 >> 1) & 3)) * 8;

  const fvec4 FZ = {0.f, 0.f, 0.f, 0.f};
  fvec4 acc[4][8];
#pragma unroll
  for (int i = 0; i < 4; ++i)
#pragma unroll
    for (int j = 0; j < 8; ++j) acc[i][j] = FZ;

  // stage one K-tile (24 segs of 1KB: segs 0-7 = A rows, 8-23 = B rows)
  auto stage = [&](bf16* dst, int ktel) {
#pragma unroll
    for (int i = 0; i < 6; ++i) {
      int s = wave * 6 + i;
      if (s < 8) {
        gll16(Ag + (size_t)(s * 16 + srow) * Kd + ktel + sc8, dst + s * 512);
      } else {
        gll16(Bg + (size_t)((s - 8) * 16 + srow) * Kd + ktel + sc8,
              dst + 4096 + (s - 8) * 512);
      }
    }
  };

  // prologue: tiles 0,1 in flight (12 outstanding vmem ops/thread)
  stage(b0, 0);
  stage(b1, 32);

  for (int t = 0; t < nt; ++t) {
    asm volatile("s_waitcnt vmcnt(6)" ::: "memory");  // retire tile t's stages
    __builtin_amdgcn_s_barrier();  // tile t visible; all tile t-1 reads consumed
    const bf16* Ab = b0;
    const bf16* Bb = b0 + 4096;
    bvec8 af[4], bv[8];
#pragma unroll
    for (int mt = 0; mt < 4; ++mt)
      af[mt] = *(const bvec8*)(Ab + (wm * 64 + mt * 16 + l15) * 32 + csw);
#pragma unroll
    for (int nt2 = 0; nt2 < 8; ++nt2)
      bv[nt2] = *(const bvec8*)(Bb + (wn * 128 + nt2 * 16 + l15) * 32 + csw);
    int t2 = t + 2;
    if (t2 >= nt) t2 = nt - 1;  // clamp keeps vmcnt ledger uniform
    stage(b2, t2 * 32);         // b2 held tile t-1, fully consumed pre-barrier
    __builtin_amdgcn_s_setprio(1);
#pragma unroll
    for (int mt = 0; mt < 4; ++mt)
#pragma unroll
      for (int nt2 = 0; nt2 < 8; ++nt2)
        acc[mt][nt2] = __builtin_amdgcn_mfma_f32_16x16x32_bf16(af[mt], bv[nt2],
                                                               acc[mt][nt2], 0, 0, 0);
    __builtin_amdgcn_s_setprio(0);
    bf16* tp = b0; b0 = b1; b1 = b2; b2 = tp;
  }

#pragma unroll
  for (int mt = 0; mt < 4; ++mt)
#pragma unroll
    for (int nt2 = 0; nt2 < 8; ++nt2)
#pragma unroll
      for (int r = 0; r < 4; ++r) {
        int row = bm * 128 + wm * 64 + mt * 16 + quad * 4 + r;
        int col = bn * 256 + wn * 128 + nt2 * 16 + l15;
        C[(size_t)row * N + col] = (OutT)acc[mt][nt2][r];
      }
}

// ---------------- causal flash attention v2 + SiLU-gate epilogue ----------------
// Block = 512 threads (8 waves), each wave owns 16 Q rows -> Q-tile = 128.
// K-tile = 64, DOUBLE-BUFFERED in LDS: stage for tile t+1 issued at the TOP
// of iter t, the end-of-iter __syncthreads (vmcnt drain) then waits on loads
// issued a full compute phase earlier -> latency hidden, ONE barrier/k-tile.
// LDS: 2x32KB K + 2x32KB V + 8x2.25KB P = 146 KB -> 1 block/CU = 8 waves/CU.
// Causal balance: 16 Q-tiles; block pairs (i, 15-i) -> exactly 34 k-tiles
// per block; grid 8x32 = 256 blocks = 1/CU. Waves fully above the diagonal
// skip compute (wave-uniform branch; barriers outside the branch).
// MASK TRIGGER (r5 bug fix): mask whenever any column can exceed the wave's
// MIN row: k0+63 > q0+wave*16 (r5 compared against max row -> leakage).
// Ks logical (row,chunk16B c): phys chunk = row*32 + (c ^ (row&31))
// Vts logical (d-row, chunk c): phys chunk = row*8  + (c ^ (row&7))
__global__ __launch_bounds__(512, 2) void flash(const bf16* __restrict__ Q,
    const bf16* __restrict__ K, const bf16* __restrict__ Vt,
    const bf16* __restrict__ QKV, bf16* __restrict__ Og) {
  __shared__ alignas(16) bf16 smem[74752];  // 2*16384 K + 2*16384 V + 9216 P

  int lin = blockIdx.x + 8 * blockIdx.y;   // 256 blocks, grid (8,32)
  int swz = (lin & 7) * 32 + (lin >> 3);   // bijective
  int pairi = swz & 7;                     // 0..7
  int bh = swz >> 3, b = bh >> 4, h = bh & 15, kvh = (h >> 2) & 3;
  int tid = threadIdx.x, wave = tid >> 6, lane = tid & 63;
  int quad = lane >> 4, l15 = lane & 15;
  bf16* Pw = smem + 65536 + wave * 1152;   // 16 x 72 bf16, private per wave

  const bf16* Qh = Q + ((size_t)(b * 16 + h) * 2048) * 256;
  const bf16* Kb = K + ((size_t)(b * 4 + kvh) * 2048) * 256;
  const bf16* Vb = Vt + ((size_t)(b * 4 + kvh) * 256) * 2048;
  const fvec4 FZ = {0.f, 0.f, 0.f, 0.f};

  // stage K-tile kt2 into buffer sel (8 gll16/wave: 4 K segs + 4 V segs)
  auto stageKV = [&](int sel, int kt2) {
    int k0s = kt2 * 64;
    bf16* Kd = smem + sel * 16384;
    bf16* Vd = smem + 32768 + sel * 16384;
#pragma unroll
    for (int i = 0; i < 4; ++i) {
      int seg = wave * 4 + i;  // 0..31, 1KB per gll16
      int krow = seg * 2 + (lane >> 5);
      int kc = (lane & 31) ^ (krow & 31);
      gll16(Kb + (size_t)(k0s + krow) * 256 + kc * 8, Kd + seg * 512);
      int vrow = seg * 8 + (lane >> 3);
      int vc = (lane & 7) ^ (vrow & 7);
      gll16(Vb + (size_t)vrow * 2048 + k0s + vc * 8, Vd + seg * 512);
    }
  };

  for (int half = 0; half < 2; ++half) {
    int qt = half ? (15 - pairi) : pairi;
    int q0 = qt * 128;
    int nkt = 2 * qt + 2;

    // Q fragments resident, pre-scaled by 1/sqrt(256)=2^-4 (exact in bf16)
    bvec8 qf[8];
    {
      int row = q0 + wave * 16 + l15;
#pragma unroll
      for (int kk = 0; kk < 8; ++kk) {
        bvec8 v = *(const bvec8*)(Qh + (size_t)row * 256 + kk * 32 + quad * 8);
#pragma unroll
        for (int j = 0; j < 8; ++j) v[j] = (bf16)((float)v[j] * 0.0625f);
        qf[kk] = v;
      }
    }

    fvec4 acc[16];
#pragma unroll
    for (int i = 0; i < 16; ++i) acc[i] = FZ;
    float m_run[4], l_run[4];
#pragma unroll
    for (int r = 0; r < 4; ++r) { m_run[r] = -3.0e38f; l_run[r] = 0.f; }

    stageKV(0, 0);
    __syncthreads();  // tile 0 resident+visible (drains vmcnt)

    for (int kt = 0; kt < nkt; ++kt) {
      int cur = kt & 1;
      if (kt + 1 < nkt) stageKV(cur ^ 1, kt + 1);  // prefetch next tile
      int k0 = kt * 64;
      const bf16* Ks = smem + cur * 16384;
      const bf16* Vts = smem + 32768 + cur * 16384;
      // wave-uniform: does this wave have any unmasked column in this tile?
      if (k0 <= q0 + wave * 16 + 15) {
        // S = Q K^T
        fvec4 s[4];
#pragma unroll
        for (int nt = 0; nt < 4; ++nt) {
          s[nt] = FZ;
          int row = nt * 16 + l15;
          int rm = row & 31;
          __builtin_amdgcn_s_setprio(1);
#pragma unroll
          for (int ks = 0; ks < 8; ++ks) {
            int c = ks * 4 + quad;
            bvec8 kf = *(const bvec8*)(Ks + (size_t)row * 256 + (size_t)(c ^ rm) * 8);
            s[nt] = __builtin_amdgcn_mfma_f32_16x16x32_bf16(qf[ks], kf, s[nt], 0, 0, 0);
          }
          __builtin_amdgcn_s_setprio(0);
        }

        if (k0 + 63 > q0 + wave * 16) {  // any column can exceed the MIN row
#pragma unroll
          for (int nt = 0; nt < 4; ++nt)
#pragma unroll
            for (int r = 0; r < 4; ++r)
              if (k0 + nt * 16 + l15 > q0 + wave * 16 + quad * 4 + r)
                s[nt][r] = -3.0e38f;
        }

        // online softmax with defer-max (THR=8)
        {
          float pmax[4];
#pragma unroll
          for (int r = 0; r < 4; ++r) {
            float m = fmaxf(fmaxf(s[0][r], s[1][r]),
                            fmaxf(s[2][r], s[3][r]));
#pragma unroll
            for (int off = 8; off; off >>= 1) m = fmaxf(m, __shfl_xor(m, off));
            pmax[r] = m;
          }
          int need = 0;
#pragma unroll
          for (int r = 0; r < 4; ++r) need |= (pmax[r] > m_run[r] + 8.0f) ? 1 : 0;
          if (__any(need)) {
#pragma unroll
            for (int r = 0; r < 4; ++r) {
              float Mn = fmaxf(m_run[r], pmax[r]);
              float alpha = __expf(m_run[r] - Mn);
              m_run[r] = Mn;
              l_run[r] *= alpha;
#pragma unroll
              for (int nt = 0; nt < 16; ++nt) acc[nt][r] *= alpha;
            }
          }
          float rs[4] = {0.f, 0.f, 0.f, 0.f};
#pragma unroll
          for (int nt = 0; nt < 4; ++nt)
#pragma unroll
            for (int r = 0; r < 4; ++r) {
              float p = __expf(s[nt][r] - m_run[r]);
              rs[r] += p;
              Pw[(quad * 4 + r) * 72 + nt * 16 + l15] = (bf16)p;
            }
#pragma unroll
          for (int r = 0; r < 4; ++r) {
#pragma unroll
            for (int off = 8; off; off >>= 1) rs[r] += __shfl_xor(rs[r], off);
            l_run[r] += rs[r];
          }
        }

        // O += P (16x64) * Vtile (64x256); same-wave P RAW -> compiler lgkmcnt
#pragma unroll
        for (int ks = 0; ks < 2; ++ks) {
          bvec8 pf = *(const bvec8*)(Pw + l15 * 72 + ks * 32 + quad * 8);
          __builtin_amdgcn_s_setprio(1);
#pragma unroll
          for (int nt = 0; nt < 16; ++nt) {
            int row = nt * 16 + l15;
            int c = ks * 4 + quad;
            bvec8 vf = *(const bvec8*)(Vts + (size_t)row * 64 + (size_t)(c ^ (row & 7)) * 8);
            acc[nt] = __builtin_amdgcn_mfma_f32_16x16x32_bf16(pf, vf, acc[nt], 0, 0, 0);
          }
          __builtin_amdgcn_s_setprio(0);
        }
      }
      __syncthreads();  // next tile resident (early-issued) + all reads of cur done
    }

    // epilogue: O/l * silu(gate), token-major (b*2048+l, h*256+d)
#pragma unroll
    for (int r = 0; r < 4; ++r) {
      int token = b * 2048 + q0 + wave * 16 + quad * 4 + r;
      float inv = 1.0f / l_run[r];
#pragma unroll
      for (int nt = 0; nt < 16; ++nt) {
        int col = h * 256 + nt * 16 + l15;
        float g = (float)QKV[(size_t)token * NQKV + 4096 + col];
        float silu = g / (1.0f + __expf(-g));
        Og[(size_t)token * 4096 + col] = (bf16)(acc[nt][r] * inv * silu);
      }
    }
  }
}

extern "C" void kernel_launch(void* const* d_in, const int* in_sizes, int n_in,
                              void* d_out, int out_size, void* d_ws, size_t ws_size,
                              hipStream_t stream) {
  const float* hs   = (const float*)d_in[0];
  const float* cosT = (const float*)d_in[1];
  const float* sinT = (const float*)d_in[2];
  const float* Wq   = (const float*)d_in[3];
  const float* Wk   = (const float*)d_in[4];
  const float* Wv   = (const float*)d_in[5];
  const float* Wo   = (const float*)d_in[6];
  const float* qw   = (const float*)d_in[7];
  const float* kw   = (const float*)d_in[8];
  float* out = (float*)d_out;

  char* p = (char*)d_ws;
  auto alloc = [&](size_t bytes) {
    char* r = p;
    p += (bytes + 255) & ~(size_t)255;
    return r;
  };
  bf16* Xb    = (bf16*)alloc((size_t)4096 * 2560 * 2);
  bf16* Wqkvt = (bf16*)alloc((size_t)10240 * 2560 * 2);
  bf16* Wot   = (bf16*)alloc((size_t)2560 * 4096 * 2);
  bf16* QKV   = (bf16*)alloc((size_t)4096 * 10240 * 2);
  bf16* Qn    = (bf16*)alloc((size_t)2 * 16 * 2048 * 256 * 2);
  bf16* Kn    = (bf16*)alloc((size_t)2 * 4 * 2048 * 256 * 2);
  bf16* Vtb   = (bf16*)alloc((size_t)2 * 4 * 256 * 2048 * 2);
  bf16* Og    = (bf16*)alloc((size_t)4096 * 4096 * 2);

  cvt_f32_bf16<<<10240, 256, 0, stream>>>(hs, Xb, 4096 * 2560);
  wtrans<<<dim3(128, 40), 256, 0, stream>>>(Wq, Wqkvt, 2560, 8192);
  wtrans<<<dim3(16, 40), 256, 0, stream>>>(Wk, Wqkvt + (size_t)8192 * 2560, 2560, 1024);
  wtrans<<<dim3(16, 40), 256, 0, stream>>>(Wv, Wqkvt + (size_t)9216 * 2560, 2560, 1024);
  wtrans<<<dim3(40, 64), 256, 0, stream>>>(Wo, Wot, 4096, 2560);

  gemm8<bf16><<<dim3(40, 32), 256, 0, stream>>>(Xb, Wqkvt, QKV, 10240, 2560);

  norm_rope<<<20480, 256, 0, stream>>>(QKV, cosT, sinT, qw, kw, Qn, Kn);
  vtrans<<<dim3(32, 4, 8), 256, 0, stream>>>(QKV, Vtb);

  flash<<<dim3(8, 32), 512, 0, stream>>>(Qn, Kn, Vtb, QKV, Og);

  gemm8<float><<<dim3(10, 32), 256, 0, stream>>>(Og, Wot, out, 2560, 4096);
}

// Round 7
// 699.218 us; speedup vs baseline: 1.0943x; 1.0377x over previous
//
#include <hip/hip_runtime.h>
#include <cstdint>
#include <cstddef>

// B=2 L=2048 HIDDEN=2560 NH=16 NKV=4 HD=256 INNER=4096
// QKV combined N = 8192 (q+gate) + 1024 (k) + 1024 (v) = 10240
#define NQKV 10240

typedef __bf16 bf16;
typedef __attribute__((ext_vector_type(4))) __bf16 bvec4;
typedef __attribute__((ext_vector_type(8))) __bf16 bvec8;
typedef __attribute__((ext_vector_type(4))) float fvec4;

__device__ __forceinline__ void gll16(const bf16* g, bf16* l) {
  // async global->LDS, 16B/lane; LDS dest = wave-uniform base + lane*16
  __builtin_amdgcn_global_load_lds(
      (const __attribute__((address_space(1))) void*)g,
      (__attribute__((address_space(3))) void*)l, 16, 0, 0);
}

// ---------------- fp32 -> bf16 flat convert ----------------
__global__ __launch_bounds__(256) void cvt_f32_bf16(const float* __restrict__ x,
                                                    bf16* __restrict__ y, int n) {
  int i = (blockIdx.x * 256 + threadIdx.x) * 4;
  if (i < n) {
    float4 v = *(const float4*)(x + i);
    bvec4 o;
    o.x = (bf16)v.x; o.y = (bf16)v.y; o.z = (bf16)v.z; o.w = (bf16)v.w;
    *(bvec4*)(y + i) = o;
  }
}

// ---------------- W (K x N) fp32 -> Wt (N x K) bf16 ----------------
__global__ __launch_bounds__(256) void wtrans(const float* __restrict__ W,
                                              bf16* __restrict__ Wt, int K, int N) {
  __shared__ float t[64][65];
  int n0 = blockIdx.x * 64, k0 = blockIdx.y * 64;
  int tx = threadIdx.x & 63, tg = threadIdx.x >> 6;
#pragma unroll
  for (int i = 0; i < 16; ++i) {
    int r = tg * 16 + i;
    t[r][tx] = W[(size_t)(k0 + r) * N + n0 + tx];
  }
  __syncthreads();
#pragma unroll
  for (int i = 0; i < 16; ++i) {
    int r = tg * 16 + i;
    Wt[(size_t)(n0 + r) * K + k0 + tx] = (bf16)t[tx][r];
  }
}

// ---------------- V columns of QKV -> Vt (b,kv,d,L) bf16 ----------------
__global__ __launch_bounds__(256) void vtrans(const bf16* __restrict__ QKV,
                                              bf16* __restrict__ Vt) {
  __shared__ bf16 t[64][65];
  int l0 = blockIdx.x * 64, dd0 = blockIdx.y * 64;
  int bkv = blockIdx.z, b = bkv >> 2, kv = bkv & 3;
  int tx = threadIdx.x & 63, tg = threadIdx.x >> 6;
#pragma unroll
  for (int i = 0; i < 16; ++i) {
    int r = tg * 16 + i;
    t[r][tx] = QKV[(size_t)(b * 2048 + l0 + r) * NQKV + 9216 + kv * 256 + dd0 + tx];
  }
  __syncthreads();
#pragma unroll
  for (int i = 0; i < 16; ++i) {
    int r = tg * 16 + i;
    Vt[((size_t)bkv * 256 + dd0 + r) * 2048 + l0 + tx] = t[tx][r];
  }
}

// ---------------- RMSNorm + RoPE: QKV -> Qn (b,h,l,d), Kn (b,kv,l,d) ----------------
__global__ __launch_bounds__(256) void norm_rope(const bf16* __restrict__ QKV,
    const float* __restrict__ cosT, const float* __restrict__ sinT,
    const float* __restrict__ qw, const float* __restrict__ kw,
    bf16* __restrict__ Qn, bf16* __restrict__ Kn) {
  int u = blockIdx.x * 4 + (threadIdx.x >> 6);
  int lane = threadIdx.x & 63;
  int token = u / 20, slot = u - token * 20;
  int b = token >> 11, l = token & 2047;
  int d0 = lane * 4;
  const float* w;
  int col0;
  bf16* outp;
  if (slot < 16) {
    col0 = slot * 256; w = qw;
    outp = Qn + ((size_t)((b * 16 + slot) * 2048 + l)) * 256;
  } else {
    int kv = slot - 16;
    col0 = 8192 + kv * 256; w = kw;
    outp = Kn + ((size_t)((b * 4 + kv) * 2048 + l)) * 256;
  }
  bvec4 xi = *(const bvec4*)(QKV + (size_t)token * NQKV + col0 + d0);
  float x[4];
#pragma unroll
  for (int j = 0; j < 4; ++j) x[j] = (float)xi[j];
  float ss = x[0] * x[0] + x[1] * x[1] + x[2] * x[2] + x[3] * x[3];
#pragma unroll
  for (int off = 32; off; off >>= 1) ss += __shfl_xor(ss, off);
  float rn = rsqrtf(ss * (1.0f / 256.0f) + 1e-6f);
  float xn[4];
#pragma unroll
  for (int j = 0; j < 4; ++j) xn[j] = x[j] * rn * w[d0 + j];
  bvec4 o;
#pragma unroll
  for (int j = 0; j < 4; ++j) {
    float other = __shfl_xor(xn[j], 32);
    float rot = (lane < 32) ? -other : other;
    float c = cosT[(size_t)l * 256 + d0 + j];
    float s = sinT[(size_t)l * 256 + d0 + j];
    o[j] = (bf16)(xn[j] * c + rot * s);
  }
  *(bvec4*)(outp + d0) = o;
}

// ---------------- 8-phase 256x256 GEMM (T2+T3+T4+T5): C = A * B^T ----------------
// BM=BN=256, BK=64. 512 threads = 8 waves (2M x 4N), per-wave out 128x64,
// acc[8][4] fvec4. LDS 128KB = 2 tile buffers x (A 32KB + B 32KB); 1 blk/CU,
// 2 waves/SIMD. Per K-tile: 4 phases; phase q = {ds_read A-subtile (4) [+ B
// (8) at q0] || stage 1 half-tile (2 gll16)} -> barrier -> lgkmcnt(0)+
// sched_barrier -> setprio(1) 16 MFMA setprio(0) -> [vmcnt(4) at q3] ->
// barrier. 2 K-tiles per iteration (even tile in buf0, odd in buf1).
// Release schedule (proof of race-freedom): a wave reads ONLY B rows
// [wn*64,+64) (all in phase q0 of a tile) and A rows [wm*128,+128) (spread
// over q0..q3) -> a tile's B region is free after its q0 barrier-2, A after
// q3 barrier-2. Stages per iter (t even): ph1-2: t+1 A-halves -> buf1 (A free
// since prev ph8); ph3-4: t+2 B-halves -> buf0 (B free after ph1); ph5-6:
// t+2 A -> buf0 (A free after ph4); ph7-8: t+3 B -> buf1 (B free after ph5).
// vmcnt ledger (2 loads per half-tile per thread): steady-state outstanding
// entering ph1 = 4; ph4 vmcnt(4) retires through t+1's A (issued ph1-2);
// ph8 vmcnt(4) retires through t+2's A (issued ph5-6). Last iter clamps the
// staged kt to nt-1 (dummy, never read).
// LDS swizzle: row of 64 bf16 = 8 x 16B chunks; logical chunk c at phys
// c ^ (row&7), applied on the gll16 GLOBAL source (dest linear) and on the
// ds_read address (both-sides rule #21).
template <typename OutT>
__global__ __launch_bounds__(512, 2) void gemm256(const bf16* __restrict__ A,
                                                  const bf16* __restrict__ B,
                                                  OutT* __restrict__ C,
                                                  int N, int Kd) {
  __shared__ alignas(16) bf16 smem[65536];  // 128 KB
  int tid = threadIdx.x, wave = tid >> 6, lane = tid & 63;
  int quad = lane >> 4, l15 = lane & 15;
  int wm = wave >> 2, wn = wave & 3;
  int bn = blockIdx.x, bm = blockIdx.y;
  const bf16* Ag = A + (size_t)bm * 256 * Kd;
  const bf16* Bg = B + (size_t)bn * 256 * Kd;

  int kx = l15 & 7;
  int arow0 = wm * 128 + l15;
  int brow0 = wn * 64 + l15;

  const fvec4 FZ = {0.f, 0.f, 0.f, 0.f};
  fvec4 acc[8][4];
#pragma unroll
  for (int i = 0; i < 8; ++i)
#pragma unroll
    for (int j = 0; j < 4; ++j) acc[i][j] = FZ;
  bvec8 bq[4][2];

  // stage one half-tile (128 rows x 64 bf16 = 16KB): 2 gll16/thread
  auto stageH = [&](int tb2, int isB, int h, int kt) {
    const bf16* G = isB ? Bg : Ag;
    bf16* base = smem + tb2 * 32768 + isB * 16384 + h * 8192;
#pragma unroll
    for (int i = 0; i < 2; ++i) {
      int sg = wave * 2 + i;                       // seg 0..15, 1KB each
      int row = h * 128 + sg * 8 + (lane >> 3);    // tile-relative row
      int c = (lane & 7) ^ ((lane >> 3) & 7);      // pre-swizzled source chunk
      gll16(G + (size_t)row * Kd + kt * 64 + c * 8, base + sg * 512);
    }
  };

#define PH(TB, Q, LOADB, STB, SISB, SH, SKT)                                   \
  {                                                                            \
    const bf16* tb_ = smem + (TB) * 32768;                                     \
    if (LOADB) {                                                               \
      _Pragma("unroll") for (int nf = 0; nf < 4; ++nf)                         \
        _Pragma("unroll") for (int s = 0; s < 2; ++s)                          \
          bq[nf][s] = *(const bvec8*)(tb_ + 16384 + (brow0 + nf * 16) * 64 +   \
                                      ((s * 4 + quad) ^ kx) * 8);              \
    }                                                                          \
    bvec8 af_[2][2];                                                           \
    _Pragma("unroll") for (int mf = 0; mf < 2; ++mf)                           \
      _Pragma("unroll") for (int s = 0; s < 2; ++s)                            \
        af_[mf][s] = *(const bvec8*)(tb_ + (arow0 + (Q) * 32 + mf * 16) * 64 + \
                                     ((s * 4 + quad) ^ kx) * 8);               \
    stageH(STB, SISB, SH, SKT);                                                \
    __builtin_amdgcn_s_barrier();                                              \
    asm volatile("s_waitcnt lgkmcnt(0)" ::: "memory");                         \
    __builtin_amdgcn_sched_barrier(0);                                         \
    __builtin_amdgcn_s_setprio(1);                                             \
    _Pragma("unroll") for (int s = 0; s < 2; ++s)                              \
      _Pragma("unroll") for (int mf = 0; mf < 2; ++mf)                         \
        _Pragma("unroll") for (int nf = 0; nf < 4; ++nf)                       \
          acc[(Q) * 2 + mf][nf] = __builtin_amdgcn_mfma_f32_16x16x32_bf16(     \
              af_[mf][s], bq[nf][s], acc[(Q) * 2 + mf][nf], 0, 0, 0);          \
    __builtin_amdgcn_s_setprio(0);                                             \
    if ((Q) == 3) asm volatile("s_waitcnt vmcnt(4)" ::: "memory");             \
    __builtin_amdgcn_s_barrier();                                              \
  }

  int nt = Kd >> 6;      // K-tiles of 64
  int ni = nt >> 1;      // 2 K-tiles per iteration

  // prologue: t0 fully + t1 B (6 half-tiles = 12 loads); retire t0 -> 4 left
  stageH(0, 1, 0, 0);
  stageH(0, 1, 1, 0);
  stageH(0, 0, 0, 0);
  stageH(0, 0, 1, 0);
  stageH(1, 1, 0, 1);
  stageH(1, 1, 1, 1);
  asm volatile("s_waitcnt vmcnt(4)" ::: "memory");
  __builtin_amdgcn_s_barrier();

  for (int it = 0; it < ni; ++it) {
    int t = it * 2;
    int tp1 = t + 1;
    int tp2 = (t + 2 < nt) ? t + 2 : nt - 1;  // clamp: dummy on last iter
    int tp3 = (t + 3 < nt) ? t + 3 : nt - 1;
    // phases 1-4: consume tile t (buf0)
    PH(0, 0, 1, 1, 0, 0, tp1)
    PH(0, 1, 0, 1, 0, 1, tp1)
    PH(0, 2, 0, 0, 1, 0, tp2)
    PH(0, 3, 0, 0, 1, 1, tp2)
    // phases 5-8: consume tile t+1 (buf1)
    PH(1, 0, 1, 0, 0, 0, tp2)
    PH(1, 1, 0, 0, 0, 1, tp2)
    PH(1, 2, 0, 1, 1, 0, tp3)
    PH(1, 3, 0, 1, 1, 1, tp3)
  }
#undef PH
  asm volatile("s_waitcnt vmcnt(0)" ::: "memory");  // drain dummy stages

#pragma unroll
  for (int am = 0; am < 8; ++am)
#pragma unroll
    for (int nf = 0; nf < 4; ++nf)
#pragma unroll
      for (int r = 0; r < 4; ++r) {
        int row = bm * 256 + wm * 128 + am * 16 + quad * 4 + r;
        int col = bn * 256 + wn * 64 + nf * 16 + l15;
        C[(size_t)row * N + col] = (OutT)acc[am][nf][r];
      }
}

// ---------------- pipelined GEMM (2nd gemm): C[M][N] = A[M][K] * B[N][K]^T ----------------
// 128x256 tile, BK=32, 4 waves, 3-buffer, one barrier per K-step, vmcnt(6).
// Kept for gemm2 (N=2560 -> only 160 blocks at 256 tile; this grid is 320).
template <typename OutT>
__global__ __launch_bounds__(256, 2) void gemm8(const bf16* __restrict__ A,
                                                const bf16* __restrict__ B,
                                                OutT* __restrict__ C,
                                                int N, int Kd) {
  __shared__ alignas(16) bf16 smem[36864];
  int tid = threadIdx.x, wave = tid >> 6, lane = tid & 63;
  int quad = lane >> 4, l15 = lane & 15;
  int wm = wave >> 1, wn = wave & 1;
  int bm = blockIdx.y, bn = blockIdx.x;
  const bf16* Ag = A + (size_t)bm * 128 * Kd;
  const bf16* Bg = B + (size_t)bn * 256 * Kd;

  bf16* b0 = smem;
  bf16* b1 = smem + 12288;
  bf16* b2 = smem + 24576;

  int nt = Kd >> 5;
  int srow = lane >> 2;
  int sc8 = ((lane & 3) ^ ((lane >> 3) & 3)) * 8;
  int csw = (quad ^ ((l15 >> 1) & 3)) * 8;

  const fvec4 FZ = {0.f, 0.f, 0.f, 0.f};
  fvec4 acc[4][8];
#pragma unroll
  for (int i = 0; i < 4; ++i)
#pragma unroll
    for (int j = 0; j < 8; ++j) acc[i][j] = FZ;

  auto stage = [&](bf16* dst, int ktel) {
#pragma unroll
    for (int i = 0; i < 6; ++i) {
      int s = wave * 6 + i;
      if (s < 8) {
        gll16(Ag + (size_t)(s * 16 + srow) * Kd + ktel + sc8, dst + s * 512);
      } else {
        gll16(Bg + (size_t)((s - 8) * 16 + srow) * Kd + ktel + sc8,
              dst + 4096 + (s - 8) * 512);
      }
    }
  };

  stage(b0, 0);
  stage(b1, 32);

  for (int t = 0; t < nt; ++t) {
    asm volatile("s_waitcnt vmcnt(6)" ::: "memory");
    __builtin_amdgcn_s_barrier();
    const bf16* Ab = b0;
    const bf16* Bb = b0 + 4096;
    bvec8 af[4], bv[8];
#pragma unroll
    for (int mt = 0; mt < 4; ++mt)
      af[mt] = *(const bvec8*)(Ab + (wm * 64 + mt * 16 + l15) * 32 + csw);
#pragma unroll
    for (int nt2 = 0; nt2 < 8; ++nt2)
      bv[nt2] = *(const bvec8*)(Bb + (wn * 128 + nt2 * 16 + l15) * 32 + csw);
    int t2 = t + 2;
    if (t2 >= nt) t2 = nt - 1;
    stage(b2, t2 * 32);
    __builtin_amdgcn_s_setprio(1);
#pragma unroll
    for (int mt = 0; mt < 4; ++mt)
#pragma unroll
      for (int nt2 = 0; nt2 < 8; ++nt2)
        acc[mt][nt2] = __builtin_amdgcn_mfma_f32_16x16x32_bf16(af[mt], bv[nt2],
                                                               acc[mt][nt2], 0, 0, 0);
    __builtin_amdgcn_s_setprio(0);
    bf16* tp = b0; b0 = b1; b1 = b2; b2 = tp;
  }

#pragma unroll
  for (int mt = 0; mt < 4; ++mt)
#pragma unroll
    for (int nt2 = 0; nt2 < 8; ++nt2)
#pragma unroll
      for (int r = 0; r < 4; ++r) {
        int row = bm * 128 + wm * 64 + mt * 16 + quad * 4 + r;
        int col = bn * 256 + wn * 128 + nt2 * 16 + l15;
        C[(size_t)row * N + col] = (OutT)acc[mt][nt2][r];
      }
}

// ---------------- causal flash attention v2 + SiLU-gate epilogue ----------------
// Block = 512 threads (8 waves), each wave owns 16 Q rows -> Q-tile = 128.
// K-tile = 64, double-buffered in LDS; prefetch at top of iter; ONE
// barrier/k-tile. LDS 146KB -> 1 block/CU. Causal pairing (i, 15-i).
__global__ __launch_bounds__(512, 2) void flash(const bf16* __restrict__ Q,
    const bf16* __restrict__ K, const bf16* __restrict__ Vt,
    const bf16* __restrict__ QKV, bf16* __restrict__ Og) {
  __shared__ alignas(16) bf16 smem[74752];  // 2*16384 K + 2*16384 V + 9216 P

  int lin = blockIdx.x + 8 * blockIdx.y;   // 256 blocks, grid (8,32)
  int swz = (lin & 7) * 32 + (lin >> 3);   // bijective
  int pairi = swz & 7;                     // 0..7
  int bh = swz >> 3, b = bh >> 4, h = bh & 15, kvh = (h >> 2) & 3;
  int tid = threadIdx.x, wave = tid >> 6, lane = tid & 63;
  int quad = lane >> 4, l15 = lane & 15;
  bf16* Pw = smem + 65536 + wave * 1152;   // 16 x 72 bf16, private per wave

  const bf16* Qh = Q + ((size_t)(b * 16 + h) * 2048) * 256;
  const bf16* Kb = K + ((size_t)(b * 4 + kvh) * 2048) * 256;
  const bf16* Vb = Vt + ((size_t)(b * 4 + kvh) * 256) * 2048;
  const fvec4 FZ = {0.f, 0.f, 0.f, 0.f};

  auto stageKV = [&](int sel, int kt2) {
    int k0s = kt2 * 64;
    bf16* Kd = smem + sel * 16384;
    bf16* Vd = smem + 32768 + sel * 16384;
#pragma unroll
    for (int i = 0; i < 4; ++i) {
      int seg = wave * 4 + i;  // 0..31, 1KB per gll16
      int krow = seg * 2 + (lane >> 5);
      int kc = (lane & 31) ^ (krow & 31);
      gll16(Kb + (size_t)(k0s + krow) * 256 + kc * 8, Kd + seg * 512);
      int vrow = seg * 8 + (lane >> 3);
      int vc = (lane & 7) ^ (vrow & 7);
      gll16(Vb + (size_t)vrow * 2048 + k0s + vc * 8, Vd + seg * 512);
    }
  };

  for (int half = 0; half < 2; ++half) {
    int qt = half ? (15 - pairi) : pairi;
    int q0 = qt * 128;
    int nkt = 2 * qt + 2;

    bvec8 qf[8];
    {
      int row = q0 + wave * 16 + l15;
#pragma unroll
      for (int kk = 0; kk < 8; ++kk) {
        bvec8 v = *(const bvec8*)(Qh + (size_t)row * 256 + kk * 32 + quad * 8);
#pragma unroll
        for (int j = 0; j < 8; ++j) v[j] = (bf16)((float)v[j] * 0.0625f);
        qf[kk] = v;
      }
    }

    fvec4 acc[16];
#pragma unroll
    for (int i = 0; i < 16; ++i) acc[i] = FZ;
    float m_run[4], l_run[4];
#pragma unroll
    for (int r = 0; r < 4; ++r) { m_run[r] = -3.0e38f; l_run[r] = 0.f; }

    stageKV(0, 0);
    __syncthreads();

    for (int kt = 0; kt < nkt; ++kt) {
      int cur = kt & 1;
      if (kt + 1 < nkt) stageKV(cur ^ 1, kt + 1);
      int k0 = kt * 64;
      const bf16* Ks = smem + cur * 16384;
      const bf16* Vts = smem + 32768 + cur * 16384;
      if (k0 <= q0 + wave * 16 + 15) {
        fvec4 s[4];
#pragma unroll
        for (int nt = 0; nt < 4; ++nt) {
          s[nt] = FZ;
          int row = nt * 16 + l15;
          int rm = row & 31;
          __builtin_amdgcn_s_setprio(1);
#pragma unroll
          for (int ks = 0; ks < 8; ++ks) {
            int c = ks * 4 + quad;
            bvec8 kf = *(const bvec8*)(Ks + (size_t)row * 256 + (size_t)(c ^ rm) * 8);
            s[nt] = __builtin_amdgcn_mfma_f32_16x16x32_bf16(qf[ks], kf, s[nt], 0, 0, 0);
          }
          __builtin_amdgcn_s_setprio(0);
        }

        if (k0 + 63 > q0 + wave * 16) {  // any column can exceed the MIN row
#pragma unroll
          for (int nt = 0; nt < 4; ++nt)
#pragma unroll
            for (int r = 0; r < 4; ++r)
              if (k0 + nt * 16 + l15 > q0 + wave * 16 + quad * 4 + r)
                s[nt][r] = -3.0e38f;
        }

        {
          float pmax[4];
#pragma unroll
          for (int r = 0; r < 4; ++r) {
            float m = fmaxf(fmaxf(s[0][r], s[1][r]),
                            fmaxf(s[2][r], s[3][r]));
#pragma unroll
            for (int off = 8; off; off >>= 1) m = fmaxf(m, __shfl_xor(m, off));
            pmax[r] = m;
          }
          int need = 0;
#pragma unroll
          for (int r = 0; r < 4; ++r) need |= (pmax[r] > m_run[r] + 8.0f) ? 1 : 0;
          if (__any(need)) {
#pragma unroll
            for (int r = 0; r < 4; ++r) {
              float Mn = fmaxf(m_run[r], pmax[r]);
              float alpha = __expf(m_run[r] - Mn);
              m_run[r] = Mn;
              l_run[r] *= alpha;
#pragma unroll
              for (int nt = 0; nt < 16; ++nt) acc[nt][r] *= alpha;
            }
          }
          float rs[4] = {0.f, 0.f, 0.f, 0.f};
#pragma unroll
          for (int nt = 0; nt < 4; ++nt)
#pragma unroll
            for (int r = 0; r < 4; ++r) {
              float p = __expf(s[nt][r] - m_run[r]);
              rs[r] += p;
              Pw[(quad * 4 + r) * 72 + nt * 16 + l15] = (bf16)p;
            }
#pragma unroll
          for (int r = 0; r < 4; ++r) {
#pragma unroll
            for (int off = 8; off; off >>= 1) rs[r] += __shfl_xor(rs[r], off);
            l_run[r] += rs[r];
          }
        }

#pragma unroll
        for (int ks = 0; ks < 2; ++ks) {
          bvec8 pf = *(const bvec8*)(Pw + l15 * 72 + ks * 32 + quad * 8);
          __builtin_amdgcn_s_setprio(1);
#pragma unroll
          for (int nt = 0; nt < 16; ++nt) {
            int row = nt * 16 + l15;
            int c = ks * 4 + quad;
            bvec8 vf = *(const bvec8*)(Vts + (size_t)row * 64 + (size_t)(c ^ (row & 7)) * 8);
            acc[nt] = __builtin_amdgcn_mfma_f32_16x16x32_bf16(pf, vf, acc[nt], 0, 0, 0);
          }
          __builtin_amdgcn_s_setprio(0);
        }
      }
      __syncthreads();
    }

#pragma unroll
    for (int r = 0; r < 4; ++r) {
      int token = b * 2048 + q0 + wave * 16 + quad * 4 + r;
      float inv = 1.0f / l_run[r];
#pragma unroll
      for (int nt = 0; nt < 16; ++nt) {
        int col = h * 256 + nt * 16 + l15;
        float g = (float)QKV[(size_t)token * NQKV + 4096 + col];
        float silu = g / (1.0f + __expf(-g));
        Og[(size_t)token * 4096 + col] = (bf16)(acc[nt][r] * inv * silu);
      }
    }
  }
}

extern "C" void kernel_launch(void* const* d_in, const int* in_sizes, int n_in,
                              void* d_out, int out_size, void* d_ws, size_t ws_size,
                              hipStream_t stream) {
  const float* hs   = (const float*)d_in[0];
  const float* cosT = (const float*)d_in[1];
  const float* sinT = (const float*)d_in[2];
  const float* Wq   = (const float*)d_in[3];
  const float* Wk   = (const float*)d_in[4];
  const float* Wv   = (const float*)d_in[5];
  const float* Wo   = (const float*)d_in[6];
  const float* qw   = (const float*)d_in[7];
  const float* kw   = (const float*)d_in[8];
  float* out = (float*)d_out;

  char* p = (char*)d_ws;
  auto alloc = [&](size_t bytes) {
    char* r = p;
    p += (bytes + 255) & ~(size_t)255;
    return r;
  };
  bf16* Xb    = (bf16*)alloc((size_t)4096 * 2560 * 2);
  bf16* Wqkvt = (bf16*)alloc((size_t)10240 * 2560 * 2);
  bf16* Wot   = (bf16*)alloc((size_t)2560 * 4096 * 2);
  bf16* QKV   = (bf16*)alloc((size_t)4096 * 10240 * 2);
  bf16* Qn    = (bf16*)alloc((size_t)2 * 16 * 2048 * 256 * 2);
  bf16* Kn    = (bf16*)alloc((size_t)2 * 4 * 2048 * 256 * 2);
  bf16* Vtb   = (bf16*)alloc((size_t)2 * 4 * 256 * 2048 * 2);
  bf16* Og    = (bf16*)alloc((size_t)4096 * 4096 * 2);

  cvt_f32_bf16<<<10240, 256, 0, stream>>>(hs, Xb, 4096 * 2560);
  wtrans<<<dim3(128, 40), 256, 0, stream>>>(Wq, Wqkvt, 2560, 8192);
  wtrans<<<dim3(16, 40), 256, 0, stream>>>(Wk, Wqkvt + (size_t)8192 * 2560, 2560, 1024);
  wtrans<<<dim3(16, 40), 256, 0, stream>>>(Wv, Wqkvt + (size_t)9216 * 2560, 2560, 1024);
  wtrans<<<dim3(40, 64), 256, 0, stream>>>(Wo, Wot, 4096, 2560);

  gemm256<bf16><<<dim3(40, 16), 512, 0, stream>>>(Xb, Wqkvt, QKV, 10240, 2560);

  norm_rope<<<20480, 256, 0, stream>>>(QKV, cosT, sinT, qw, kw, Qn, Kn);
  vtrans<<<dim3(32, 4, 8), 256, 0, stream>>>(QKV, Vtb);

  flash<<<dim3(8, 32), 512, 0, stream>>>(Qn, Kn, Vtb, QKV, Og);

  gemm8<float><<<dim3(10, 32), 256, 0, stream>>>(Og, Wot, out, 2560, 4096);
}

// Round 8
// 698.983 us; speedup vs baseline: 1.0946x; 1.0003x over previous
//
#include <hip/hip_runtime.h>
#include <cstdint>
#include <cstddef>

// B=2 L=2048 HIDDEN=2560 NH=16 NKV=4 HD=256 INNER=4096
// QKV combined N = 8192 (q+gate) + 1024 (k) + 1024 (v) = 10240
#define NQKV 10240

typedef __bf16 bf16;
typedef __attribute__((ext_vector_type(4))) __bf16 bvec4;
typedef __attribute__((ext_vector_type(8))) __bf16 bvec8;
typedef __attribute__((ext_vector_type(4))) float fvec4;

__device__ __forceinline__ void gll16(const bf16* g, bf16* l) {
  // async global->LDS, 16B/lane; LDS dest = wave-uniform base + lane*16
  __builtin_amdgcn_global_load_lds(
      (const __attribute__((address_space(1))) void*)g,
      (__attribute__((address_space(3))) void*)l, 16, 0, 0);
}

// ---------------- fp32 -> bf16 flat convert ----------------
__global__ __launch_bounds__(256) void cvt_f32_bf16(const float* __restrict__ x,
                                                    bf16* __restrict__ y, int n) {
  int i = (blockIdx.x * 256 + threadIdx.x) * 4;
  if (i < n) {
    float4 v = *(const float4*)(x + i);
    bvec4 o;
    o.x = (bf16)v.x; o.y = (bf16)v.y; o.z = (bf16)v.z; o.w = (bf16)v.w;
    *(bvec4*)(y + i) = o;
  }
}

// ---------------- W (K x N) fp32 -> Wt (N x K) bf16 (vectorized) ----------------
// Phase 1: float4 global reads (256B/quarter-wave contiguous), 4 scalar LDS
// writes, banks (r+c)%32 all-distinct-mod-2 -> conflict-free.
// Phase 2: 8 scalar LDS reads at stride 65 rows -> banks (8m+j+n)%32, 2-way
// (free); bvec8 (16B) global writes, 8 lanes = 128B contiguous per row.
__global__ __launch_bounds__(256) void wtrans(const float* __restrict__ W,
                                              bf16* __restrict__ Wt, int K, int N) {
  __shared__ float t[64][65];
  int n0 = blockIdx.x * 64, k0 = blockIdx.y * 64;
  int tid = threadIdx.x;
#pragma unroll
  for (int it = 0; it < 4; ++it) {
    int idx = it * 256 + tid;            // 0..1023
    int r = idx >> 4, c4 = (idx & 15) * 4;
    float4 v = *(const float4*)&W[(size_t)(k0 + r) * N + n0 + c4];
    t[r][c4 + 0] = v.x; t[r][c4 + 1] = v.y;
    t[r][c4 + 2] = v.z; t[r][c4 + 3] = v.w;
  }
  __syncthreads();
#pragma unroll
  for (int it = 0; it < 2; ++it) {
    int idx = it * 256 + tid;            // 0..511
    int n = idx >> 3, o = (idx & 7) * 8;
    bvec8 v;
#pragma unroll
    for (int j = 0; j < 8; ++j) v[j] = (bf16)t[o + j][n];
    *(bvec8*)&Wt[(size_t)(n0 + n) * K + k0 + o] = v;
  }
}

// ---------------- V columns of QKV -> Vt (b,kv,d,L) bf16 ----------------
__global__ __launch_bounds__(256) void vtrans(const bf16* __restrict__ QKV,
                                              bf16* __restrict__ Vt) {
  __shared__ bf16 t[64][65];
  int l0 = blockIdx.x * 64, dd0 = blockIdx.y * 64;
  int bkv = blockIdx.z, b = bkv >> 2, kv = bkv & 3;
  int tx = threadIdx.x & 63, tg = threadIdx.x >> 6;
#pragma unroll
  for (int i = 0; i < 16; ++i) {
    int r = tg * 16 + i;
    t[r][tx] = QKV[(size_t)(b * 2048 + l0 + r) * NQKV + 9216 + kv * 256 + dd0 + tx];
  }
  __syncthreads();
#pragma unroll
  for (int i = 0; i < 16; ++i) {
    int r = tg * 16 + i;
    Vt[((size_t)bkv * 256 + dd0 + r) * 2048 + l0 + tx] = t[tx][r];
  }
}

// ---------------- RMSNorm + RoPE: QKV -> Qn (b,h,l,d), Kn (b,kv,l,d) ----------------
__global__ __launch_bounds__(256) void norm_rope(const bf16* __restrict__ QKV,
    const float* __restrict__ cosT, const float* __restrict__ sinT,
    const float* __restrict__ qw, const float* __restrict__ kw,
    bf16* __restrict__ Qn, bf16* __restrict__ Kn) {
  int u = blockIdx.x * 4 + (threadIdx.x >> 6);
  int lane = threadIdx.x & 63;
  int token = u / 20, slot = u - token * 20;
  int b = token >> 11, l = token & 2047;
  int d0 = lane * 4;
  const float* w;
  int col0;
  bf16* outp;
  if (slot < 16) {
    col0 = slot * 256; w = qw;
    outp = Qn + ((size_t)((b * 16 + slot) * 2048 + l)) * 256;
  } else {
    int kv = slot - 16;
    col0 = 8192 + kv * 256; w = kw;
    outp = Kn + ((size_t)((b * 4 + kv) * 2048 + l)) * 256;
  }
  bvec4 xi = *(const bvec4*)(QKV + (size_t)token * NQKV + col0 + d0);
  float x[4];
#pragma unroll
  for (int j = 0; j < 4; ++j) x[j] = (float)xi[j];
  float ss = x[0] * x[0] + x[1] * x[1] + x[2] * x[2] + x[3] * x[3];
#pragma unroll
  for (int off = 32; off; off >>= 1) ss += __shfl_xor(ss, off);
  float rn = rsqrtf(ss * (1.0f / 256.0f) + 1e-6f);
  float xn[4];
#pragma unroll
  for (int j = 0; j < 4; ++j) xn[j] = x[j] * rn * w[d0 + j];
  bvec4 o;
#pragma unroll
  for (int j = 0; j < 4; ++j) {
    float other = __shfl_xor(xn[j], 32);
    float rot = (lane < 32) ? -other : other;
    float c = cosT[(size_t)l * 256 + d0 + j];
    float s = sinT[(size_t)l * 256 + d0 + j];
    o[j] = (bf16)(xn[j] * c + rot * s);
  }
  *(bvec4*)(outp + d0) = o;
}

// ---------------- 8-phase 256x256 GEMM (T2+T3+T4+T5): C = A * B^T ----------------
// Same verified structure as r7. Now launched on the q+gate columns only:
// grid (32,16) = 512 blocks = 2 EXACT rounds at 1 block/CU (the 640-block
// r7 grid ran 2.5 rounds -> 3 with a half-idle tail, costing ~17%).
template <typename OutT>
__global__ __launch_bounds__(512, 2) void gemm256(const bf16* __restrict__ A,
                                                  const bf16* __restrict__ B,
                                                  OutT* __restrict__ C,
                                                  int N, int Kd) {
  __shared__ alignas(16) bf16 smem[65536];  // 128 KB
  int tid = threadIdx.x, wave = tid >> 6, lane = tid & 63;
  int quad = lane >> 4, l15 = lane & 15;
  int wm = wave >> 2, wn = wave & 3;
  int bn = blockIdx.x, bm = blockIdx.y;
  const bf16* Ag = A + (size_t)bm * 256 * Kd;
  const bf16* Bg = B + (size_t)bn * 256 * Kd;

  int kx = l15 & 7;
  int arow0 = wm * 128 + l15;
  int brow0 = wn * 64 + l15;

  const fvec4 FZ = {0.f, 0.f, 0.f, 0.f};
  fvec4 acc[8][4];
#pragma unroll
  for (int i = 0; i < 8; ++i)
#pragma unroll
    for (int j = 0; j < 4; ++j) acc[i][j] = FZ;
  bvec8 bq[4][2];

  // stage one half-tile (128 rows x 64 bf16 = 16KB): 2 gll16/thread
  auto stageH = [&](int tb2, int isB, int h, int kt) {
    const bf16* G = isB ? Bg : Ag;
    bf16* base = smem + tb2 * 32768 + isB * 16384 + h * 8192;
#pragma unroll
    for (int i = 0; i < 2; ++i) {
      int sg = wave * 2 + i;                       // seg 0..15, 1KB each
      int row = h * 128 + sg * 8 + (lane >> 3);    // tile-relative row
      int c = (lane & 7) ^ ((lane >> 3) & 7);      // pre-swizzled source chunk
      gll16(G + (size_t)row * Kd + kt * 64 + c * 8, base + sg * 512);
    }
  };

#define PH(TB, Q, LOADB, STB, SISB, SH, SKT)                                   \
  {                                                                            \
    const bf16* tb_ = smem + (TB) * 32768;                                     \
    if (LOADB) {                                                               \
      _Pragma("unroll") for (int nf = 0; nf < 4; ++nf)                         \
        _Pragma("unroll") for (int s = 0; s < 2; ++s)                          \
          bq[nf][s] = *(const bvec8*)(tb_ + 16384 + (brow0 + nf * 16) * 64 +   \
                                      ((s * 4 + quad) ^ kx) * 8);              \
    }                                                                          \
    bvec8 af_[2][2];                                                           \
    _Pragma("unroll") for (int mf = 0; mf < 2; ++mf)                           \
      _Pragma("unroll") for (int s = 0; s < 2; ++s)                            \
        af_[mf][s] = *(const bvec8*)(tb_ + (arow0 + (Q) * 32 + mf * 16) * 64 + \
                                     ((s * 4 + quad) ^ kx) * 8);               \
    stageH(STB, SISB, SH, SKT);                                                \
    __builtin_amdgcn_s_barrier();                                              \
    asm volatile("s_waitcnt lgkmcnt(0)" ::: "memory");                         \
    __builtin_amdgcn_sched_barrier(0);                                         \
    __builtin_amdgcn_s_setprio(1);                                             \
    _Pragma("unroll") for (int s = 0; s < 2; ++s)                              \
      _Pragma("unroll") for (int mf = 0; mf < 2; ++mf)                         \
        _Pragma("unroll") for (int nf = 0; nf < 4; ++nf)                       \
          acc[(Q) * 2 + mf][nf] = __builtin_amdgcn_mfma_f32_16x16x32_bf16(     \
              af_[mf][s], bq[nf][s], acc[(Q) * 2 + mf][nf], 0, 0, 0);          \
    __builtin_amdgcn_s_setprio(0);                                             \
    if ((Q) == 3) asm volatile("s_waitcnt vmcnt(4)" ::: "memory");             \
    __builtin_amdgcn_s_barrier();                                              \
  }

  int nt = Kd >> 6;      // K-tiles of 64
  int ni = nt >> 1;      // 2 K-tiles per iteration

  // prologue: t0 fully + t1 B (6 half-tiles = 12 loads); retire t0 -> 4 left
  stageH(0, 1, 0, 0);
  stageH(0, 1, 1, 0);
  stageH(0, 0, 0, 0);
  stageH(0, 0, 1, 0);
  stageH(1, 1, 0, 1);
  stageH(1, 1, 1, 1);
  asm volatile("s_waitcnt vmcnt(4)" ::: "memory");
  __builtin_amdgcn_s_barrier();

  for (int it = 0; it < ni; ++it) {
    int t = it * 2;
    int tp1 = t + 1;
    int tp2 = (t + 2 < nt) ? t + 2 : nt - 1;  // clamp: dummy on last iter
    int tp3 = (t + 3 < nt) ? t + 3 : nt - 1;
    // phases 1-4: consume tile t (buf0)
    PH(0, 0, 1, 1, 0, 0, tp1)
    PH(0, 1, 0, 1, 0, 1, tp1)
    PH(0, 2, 0, 0, 1, 0, tp2)
    PH(0, 3, 0, 0, 1, 1, tp2)
    // phases 5-8: consume tile t+1 (buf1)
    PH(1, 0, 1, 0, 0, 0, tp2)
    PH(1, 1, 0, 0, 0, 1, tp2)
    PH(1, 2, 0, 1, 1, 0, tp3)
    PH(1, 3, 0, 1, 1, 1, tp3)
  }
#undef PH
  asm volatile("s_waitcnt vmcnt(0)" ::: "memory");  // drain dummy stages

#pragma unroll
  for (int am = 0; am < 8; ++am)
#pragma unroll
    for (int nf = 0; nf < 4; ++nf)
#pragma unroll
      for (int r = 0; r < 4; ++r) {
        int row = bm * 256 + wm * 128 + am * 16 + quad * 4 + r;
        int col = bn * 256 + wn * 64 + nf * 16 + l15;
        C[(size_t)row * N + col] = (OutT)acc[am][nf][r];
      }
}

// ---------------- pipelined GEMM, 128x128 tile: C = A * B^T ----------------
// Derivative of the verified gemm8 (r4): BK=32, 4 waves (2M x 2N), per-wave
// 64x64 -> acc[4][4], 16 MFMA + 8 ds_read_b128 per K-step. LDS: 3 buffers x
// (A 8KB + B 8KB) = 48KB -> 3 blocks/CU (12 waves/CU). ONE barrier per
// K-step; vmcnt(4) retires current tile's 4 stages (2 tiles in flight).
// Same both-sides chunk swizzle as gemm8. Used for: (a) the k/v columns of
// the QKV gemm (grid 16x32, all-resident) and (b) gemm2 (grid 20x32,
// all-resident -- the old 128x256/320-block config double-loaded 64 CUs).
template <typename OutT>
__global__ __launch_bounds__(256, 3) void gemm8n(const bf16* __restrict__ A,
                                                 const bf16* __restrict__ B,
                                                 OutT* __restrict__ C,
                                                 int N, int Kd) {
  __shared__ alignas(16) bf16 smem[24576];  // 3 x 8192 bf16 = 48 KB
  int tid = threadIdx.x, wave = tid >> 6, lane = tid & 63;
  int quad = lane >> 4, l15 = lane & 15;
  int wm = wave >> 1, wn = wave & 1;
  int bm = blockIdx.y, bn = blockIdx.x;
  const bf16* Ag = A + (size_t)bm * 128 * Kd;
  const bf16* Bg = B + (size_t)bn * 128 * Kd;

  bf16* b0 = smem;
  bf16* b1 = smem + 8192;
  bf16* b2 = smem + 16384;

  int nt = Kd >> 5;
  int srow = lane >> 2;
  int sc8 = ((lane & 3) ^ ((lane >> 3) & 3)) * 8;
  int csw = (quad ^ ((l15 >> 1) & 3)) * 8;

  const fvec4 FZ = {0.f, 0.f, 0.f, 0.f};
  fvec4 acc[4][4];
#pragma unroll
  for (int i = 0; i < 4; ++i)
#pragma unroll
    for (int j = 0; j < 4; ++j) acc[i][j] = FZ;

  // stage one K-tile (16 segs of 1KB: 0-7 = A rows, 8-15 = B rows)
  auto stage = [&](bf16* dst, int ktel) {
#pragma unroll
    for (int i = 0; i < 4; ++i) {
      int s = wave * 4 + i;
      if (s < 8) {
        gll16(Ag + (size_t)(s * 16 + srow) * Kd + ktel + sc8, dst + s * 512);
      } else {
        gll16(Bg + (size_t)((s - 8) * 16 + srow) * Kd + ktel + sc8,
              dst + 4096 + (s - 8) * 512);
      }
    }
  };

  stage(b0, 0);
  stage(b1, 32);

  for (int t = 0; t < nt; ++t) {
    asm volatile("s_waitcnt vmcnt(4)" ::: "memory");  // retire tile t's stages
    __builtin_amdgcn_s_barrier();  // tile t visible; tile t-1 fully consumed
    const bf16* Ab = b0;
    const bf16* Bb = b0 + 4096;
    bvec8 af[4], bv[4];
#pragma unroll
    for (int mt = 0; mt < 4; ++mt)
      af[mt] = *(const bvec8*)(Ab + (wm * 64 + mt * 16 + l15) * 32 + csw);
#pragma unroll
    for (int nt2 = 0; nt2 < 4; ++nt2)
      bv[nt2] = *(const bvec8*)(Bb + (wn * 64 + nt2 * 16 + l15) * 32 + csw);
    int t2 = t + 2;
    if (t2 >= nt) t2 = nt - 1;  // clamp keeps vmcnt ledger uniform
    stage(b2, t2 * 32);
    __builtin_amdgcn_s_setprio(1);
#pragma unroll
    for (int mt = 0; mt < 4; ++mt)
#pragma unroll
      for (int nt2 = 0; nt2 < 4; ++nt2)
        acc[mt][nt2] = __builtin_amdgcn_mfma_f32_16x16x32_bf16(af[mt], bv[nt2],
                                                               acc[mt][nt2], 0, 0, 0);
    __builtin_amdgcn_s_setprio(0);
    bf16* tp = b0; b0 = b1; b1 = b2; b2 = tp;
  }

#pragma unroll
  for (int mt = 0; mt < 4; ++mt)
#pragma unroll
    for (int nt2 = 0; nt2 < 4; ++nt2)
#pragma unroll
      for (int r = 0; r < 4; ++r) {
        int row = bm * 128 + wm * 64 + mt * 16 + quad * 4 + r;
        int col = bn * 128 + wn * 64 + nt2 * 16 + l15;
        C[(size_t)row * N + col] = (OutT)acc[mt][nt2][r];
      }
}

// ---------------- causal flash attention v2 + SiLU-gate epilogue ----------------
// Block = 512 threads (8 waves), each wave owns 16 Q rows -> Q-tile = 128.
// K-tile = 64, double-buffered in LDS; prefetch at top of iter; ONE
// barrier/k-tile. LDS 146KB -> 1 block/CU. Causal pairing (i, 15-i).
__global__ __launch_bounds__(512, 2) void flash(const bf16* __restrict__ Q,
    const bf16* __restrict__ K, const bf16* __restrict__ Vt,
    const bf16* __restrict__ QKV, bf16* __restrict__ Og) {
  __shared__ alignas(16) bf16 smem[74752];  // 2*16384 K + 2*16384 V + 9216 P

  int lin = blockIdx.x + 8 * blockIdx.y;   // 256 blocks, grid (8,32)
  int swz = (lin & 7) * 32 + (lin >> 3);   // bijective
  int pairi = swz & 7;                     // 0..7
  int bh = swz >> 3, b = bh >> 4, h = bh & 15, kvh = (h >> 2) & 3;
  int tid = threadIdx.x, wave = tid >> 6, lane = tid & 63;
  int quad = lane >> 4, l15 = lane & 15;
  bf16* Pw = smem + 65536 + wave * 1152;   // 16 x 72 bf16, private per wave

  const bf16* Qh = Q + ((size_t)(b * 16 + h) * 2048) * 256;
  const bf16* Kb = K + ((size_t)(b * 4 + kvh) * 2048) * 256;
  const bf16* Vb = Vt + ((size_t)(b * 4 + kvh) * 256) * 2048;
  const fvec4 FZ = {0.f, 0.f, 0.f, 0.f};

  auto stageKV = [&](int sel, int kt2) {
    int k0s = kt2 * 64;
    bf16* Kd = smem + sel * 16384;
    bf16* Vd = smem + 32768 + sel * 16384;
#pragma unroll
    for (int i = 0; i < 4; ++i) {
      int seg = wave * 4 + i;  // 0..31, 1KB per gll16
      int krow = seg * 2 + (lane >> 5);
      int kc = (lane & 31) ^ (krow & 31);
      gll16(Kb + (size_t)(k0s + krow) * 256 + kc * 8, Kd + seg * 512);
      int vrow = seg * 8 + (lane >> 3);
      int vc = (lane & 7) ^ (vrow & 7);
      gll16(Vb + (size_t)vrow * 2048 + k0s + vc * 8, Vd + seg * 512);
    }
  };

  for (int half = 0; half < 2; ++half) {
    int qt = half ? (15 - pairi) : pairi;
    int q0 = qt * 128;
    int nkt = 2 * qt + 2;

    bvec8 qf[8];
    {
      int row = q0 + wave * 16 + l15;
#pragma unroll
      for (int kk = 0; kk < 8; ++kk) {
        bvec8 v = *(const bvec8*)(Qh + (size_t)row * 256 + kk * 32 + quad * 8);
#pragma unroll
        for (int j = 0; j < 8; ++j) v[j] = (bf16)((float)v[j] * 0.0625f);
        qf[kk] = v;
      }
    }

    fvec4 acc[16];
#pragma unroll
    for (int i = 0; i < 16; ++i) acc[i] = FZ;
    float m_run[4], l_run[4];
#pragma unroll
    for (int r = 0; r < 4; ++r) { m_run[r] = -3.0e38f; l_run[r] = 0.f; }

    stageKV(0, 0);
    __syncthreads();

    for (int kt = 0; kt < nkt; ++kt) {
      int cur = kt & 1;
      if (kt + 1 < nkt) stageKV(cur ^ 1, kt + 1);
      int k0 = kt * 64;
      const bf16* Ks = smem + cur * 16384;
      const bf16* Vts = smem + 32768 + cur * 16384;
      if (k0 <= q0 + wave * 16 + 15) {
        fvec4 s[4];
#pragma unroll
        for (int nt = 0; nt < 4; ++nt) {
          s[nt] = FZ;
          int row = nt * 16 + l15;
          int rm = row & 31;
          __builtin_amdgcn_s_setprio(1);
#pragma unroll
          for (int ks = 0; ks < 8; ++ks) {
            int c = ks * 4 + quad;
            bvec8 kf = *(const bvec8*)(Ks + (size_t)row * 256 + (size_t)(c ^ rm) * 8);
            s[nt] = __builtin_amdgcn_mfma_f32_16x16x32_bf16(qf[ks], kf, s[nt], 0, 0, 0);
          }
          __builtin_amdgcn_s_setprio(0);
        }

        if (k0 + 63 > q0 + wave * 16) {  // any column can exceed the MIN row
#pragma unroll
          for (int nt = 0; nt < 4; ++nt)
#pragma unroll
            for (int r = 0; r < 4; ++r)
              if (k0 + nt * 16 + l15 > q0 + wave * 16 + quad * 4 + r)
                s[nt][r] = -3.0e38f;
        }

        {
          float pmax[4];
#pragma unroll
          for (int r = 0; r < 4; ++r) {
            float m = fmaxf(fmaxf(s[0][r], s[1][r]),
                            fmaxf(s[2][r], s[3][r]));
#pragma unroll
            for (int off = 8; off; off >>= 1) m = fmaxf(m, __shfl_xor(m, off));
            pmax[r] = m;
          }
          int need = 0;
#pragma unroll
          for (int r = 0; r < 4; ++r) need |= (pmax[r] > m_run[r] + 8.0f) ? 1 : 0;
          if (__any(need)) {
#pragma unroll
            for (int r = 0; r < 4; ++r) {
              float Mn = fmaxf(m_run[r], pmax[r]);
              float alpha = __expf(m_run[r] - Mn);
              m_run[r] = Mn;
              l_run[r] *= alpha;
#pragma unroll
              for (int nt = 0; nt < 16; ++nt) acc[nt][r] *= alpha;
            }
          }
          float rs[4] = {0.f, 0.f, 0.f, 0.f};
#pragma unroll
          for (int nt = 0; nt < 4; ++nt)
#pragma unroll
            for (int r = 0; r < 4; ++r) {
              float p = __expf(s[nt][r] - m_run[r]);
              rs[r] += p;
              Pw[(quad * 4 + r) * 72 + nt * 16 + l15] = (bf16)p;
            }
#pragma unroll
          for (int r = 0; r < 4; ++r) {
#pragma unroll
            for (int off = 8; off; off >>= 1) rs[r] += __shfl_xor(rs[r], off);
            l_run[r] += rs[r];
          }
        }

#pragma unroll
        for (int ks = 0; ks < 2; ++ks) {
          bvec8 pf = *(const bvec8*)(Pw + l15 * 72 + ks * 32 + quad * 8);
          __builtin_amdgcn_s_setprio(1);
#pragma unroll
          for (int nt = 0; nt < 16; ++nt) {
            int row = nt * 16 + l15;
            int c = ks * 4 + quad;
            bvec8 vf = *(const bvec8*)(Vts + (size_t)row * 64 + (size_t)(c ^ (row & 7)) * 8);
            acc[nt] = __builtin_amdgcn_mfma_f32_16x16x32_bf16(pf, vf, acc[nt], 0, 0, 0);
          }
          __builtin_amdgcn_s_setprio(0);
        }
      }
      __syncthreads();
    }

#pragma unroll
    for (int r = 0; r < 4; ++r) {
      int token = b * 2048 + q0 + wave * 16 + quad * 4 + r;
      float inv = 1.0f / l_run[r];
#pragma unroll
      for (int nt = 0; nt < 16; ++nt) {
        int col = h * 256 + nt * 16 + l15;
        float g = (float)QKV[(size_t)token * NQKV + 4096 + col];
        float silu = g / (1.0f + __expf(-g));
        Og[(size_t)token * 4096 + col] = (bf16)(acc[nt][r] * inv * silu);
      }
    }
  }
}

extern "C" void kernel_launch(void* const* d_in, const int* in_sizes, int n_in,
                              void* d_out, int out_size, void* d_ws, size_t ws_size,
                              hipStream_t stream) {
  const float* hs   = (const float*)d_in[0];
  const float* cosT = (const float*)d_in[1];
  const float* sinT = (const float*)d_in[2];
  const float* Wq   = (const float*)d_in[3];
  const float* Wk   = (const float*)d_in[4];
  const float* Wv   = (const float*)d_in[5];
  const float* Wo   = (const float*)d_in[6];
  const float* qw   = (const float*)d_in[7];
  const float* kw   = (const float*)d_in[8];
  float* out = (float*)d_out;

  char* p = (char*)d_ws;
  auto alloc = [&](size_t bytes) {
    char* r = p;
    p += (bytes + 255) & ~(size_t)255;
    return r;
  };
  bf16* Xb    = (bf16*)alloc((size_t)4096 * 2560 * 2);
  bf16* Wqkvt = (bf16*)alloc((size_t)10240 * 2560 * 2);
  bf16* Wot   = (bf16*)alloc((size_t)2560 * 4096 * 2);
  bf16* QKV   = (bf16*)alloc((size_t)4096 * 10240 * 2);
  bf16* Qn    = (bf16*)alloc((size_t)2 * 16 * 2048 * 256 * 2);
  bf16* Kn    = (bf16*)alloc((size_t)2 * 4 * 2048 * 256 * 2);
  bf16* Vtb   = (bf16*)alloc((size_t)2 * 4 * 256 * 2048 * 2);
  bf16* Og    = (bf16*)alloc((size_t)4096 * 4096 * 2);

  cvt_f32_bf16<<<10240, 256, 0, stream>>>(hs, Xb, 4096 * 2560);
  wtrans<<<dim3(128, 40), 256, 0, stream>>>(Wq, Wqkvt, 2560, 8192);
  wtrans<<<dim3(16, 40), 256, 0, stream>>>(Wk, Wqkvt + (size_t)8192 * 2560, 2560, 1024);
  wtrans<<<dim3(16, 40), 256, 0, stream>>>(Wv, Wqkvt + (size_t)9216 * 2560, 2560, 1024);
  wtrans<<<dim3(40, 64), 256, 0, stream>>>(Wo, Wot, 4096, 2560);

  // QKV gemm split: q+gate (8192 cols) on the 8-phase 256^2 kernel with an
  // EXACT 2-round grid; k/v (2048 cols) on the 128^2 all-resident pipeline.
  gemm256<bf16><<<dim3(32, 16), 512, 0, stream>>>(Xb, Wqkvt, QKV, 10240, 2560);
  gemm8n<bf16><<<dim3(16, 32), 256, 0, stream>>>(
      Xb, Wqkvt + (size_t)8192 * 2560, QKV + 8192, 10240, 2560);

  norm_rope<<<20480, 256, 0, stream>>>(QKV, cosT, sinT, qw, kw, Qn, Kn);
  vtrans<<<dim3(32, 4, 8), 256, 0, stream>>>(QKV, Vtb);

  flash<<<dim3(8, 32), 512, 0, stream>>>(Qn, Kn, Vtb, QKV, Og);

  gemm8n<float><<<dim3(20, 32), 256, 0, stream>>>(Og, Wot, out, 2560, 4096);
}